// Round 14
// baseline (2484.880 us; speedup 1.0000x reference)
//
#include <hip/hip_runtime.h>
#include <stdint.h>

#define L2E 1.4426950408889634f

typedef __attribute__((ext_vector_type(8))) short short8;
typedef __attribute__((ext_vector_type(4))) float floatx4;
typedef __attribute__((ext_vector_type(4))) unsigned int uintx4;
typedef __attribute__((ext_vector_type(2))) _Float16 half2v;

__device__ __forceinline__ uint32_t pkbf(float lo, float hi) {
  uint32_t r;
  asm("v_cvt_pk_bf16_f32 %0, %1, %2" : "=v"(r) : "v"(lo), "v"(hi));
  return r;
}
__device__ __forceinline__ uint32_t pkh(float lo, float hi) {
  uint32_t r;
  asm("v_cvt_pkrtz_f16_f32 %0, %1, %2" : "=v"(r) : "v"(lo), "v"(hi));
  return r;
}
__device__ __forceinline__ float2 uph(uint32_t u) {
  union { uint32_t u; half2v h; } z; z.u = u;
  return make_float2((float)z.h.x, (float)z.h.y);
}
__device__ __forceinline__ short8 mkfrag(const float* p) {
  float4 a = *(const float4*)p;
  float4 b = *(const float4*)(p + 4);
  union { uint32_t u[4]; short8 s; } z;
  z.u[0] = pkbf(a.x, a.y); z.u[1] = pkbf(a.z, a.w);
  z.u[2] = pkbf(b.x, b.y); z.u[3] = pkbf(b.z, b.w);
  return z.s;
}
__device__ __forceinline__ short8 pk8(float4 a, float4 b) {
  union { uint32_t u[4]; short8 s; } z;
  z.u[0] = pkbf(a.x, a.y); z.u[1] = pkbf(a.z, a.w);
  z.u[2] = pkbf(b.x, b.y); z.u[3] = pkbf(b.z, b.w);
  return z.s;
}
__device__ __forceinline__ short8 u4s8(uint32_t a, uint32_t b, uint32_t c, uint32_t d) {
  union { uint32_t u[4]; short8 s; } z;
  z.u[0] = a; z.u[1] = b; z.u[2] = c; z.u[3] = d;
  return z.s;
}

#define SWAP32(a, b) asm("v_permlane32_swap_b32 %0, %1" : "+v"(a), "+v"(b))
#define SWAP16(a, b) asm("v_permlane16_swap_b32 %0, %1" : "+v"(a), "+v"(b))
#define GLDS16(gp, lp) __builtin_amdgcn_global_load_lds( \
    (const __attribute__((address_space(1))) void*)(gp), \
    (__attribute__((address_space(3))) void*)(lp), 16, 0, 0)

// ============ G1: preg f16 + mx f16 / m1 f32 (R11/R13 layouts, unchanged) ============
__global__ __launch_bounds__(256) void g1_pre(
    const float* __restrict__ values, const float* __restrict__ masks,
    const float* __restrict__ W_ih, const float* __restrict__ b_ih,
    const float* __restrict__ b_hh, uint2* __restrict__ pregS,
    uint2* __restrict__ mxS, float* __restrict__ m1S, int gstride)
{
  const int tid = threadIdx.x, wv = tid >> 6, l = tid & 63;
  const int c = l & 15, kw = l >> 4;
  const int tch = blockIdx.x, gr = blockIdx.y;
  const int tbase = tch * 8;

  short8 WF[8][4];
  #pragma unroll
  for (int tg = 0; tg < 8; ++tg)
    #pragma unroll
    for (int kc = 0; kc < 4; ++kc)
      WF[tg][kc] = mkfrag(W_ih + (size_t)(16*tg + c)*128 + 32*kc + 8*kw);

  float4 bias[8];
  #pragma unroll
  for (int tg = 0; tg < 8; ++tg) {
    float4 bi = *(const float4*)(b_ih + 16*tg + 4*kw);
    float4 bh = *(const float4*)(b_hh + 16*tg + 4*kw);
    bias[tg] = make_float4(bi.x+bh.x, bi.y+bh.y, bi.z+bh.z, bi.w+bh.w);
  }

  #pragma unroll 1
  for (int tt = 0; tt < 2; ++tt) {
    const int rec = tbase + wv*2 + tt;
    const size_t ibase = ((size_t)(gr*16 + c)*2048 + rec)*64;
    const float* xr = values + ibase;
    const float* mr = masks + ibase;
    float4 xa0 = *(const float4*)(xr + 8*kw),      xa1 = *(const float4*)(xr + 8*kw + 4);
    float4 xb0 = *(const float4*)(xr + 32 + 8*kw), xb1 = *(const float4*)(xr + 32 + 8*kw + 4);
    float4 ma0 = *(const float4*)(mr + 8*kw),      ma1 = *(const float4*)(mr + 8*kw + 4);
    float4 mb0 = *(const float4*)(mr + 32 + 8*kw), mb1 = *(const float4*)(mr + 32 + 8*kw + 4);
    float4 fa0 = make_float4(xa0.x*ma0.x, xa0.y*ma0.y, xa0.z*ma0.z, xa0.w*ma0.w);
    float4 fa1 = make_float4(xa1.x*ma1.x, xa1.y*ma1.y, xa1.z*ma1.z, xa1.w*ma1.w);
    float4 fb0 = make_float4(xb0.x*mb0.x, xb0.y*mb0.y, xb0.z*mb0.z, xb0.w*mb0.w);
    float4 fb1 = make_float4(xb1.x*mb1.x, xb1.y*mb1.y, xb1.z*mb1.z, xb1.w*mb1.w);

    short8 BF0 = pk8(fa0, fa1), BF1 = pk8(fb0, fb1);
    short8 BF2 = pk8(ma0, ma1), BF3 = pk8(mb0, mb1);

    floatx4 acc[8];
    #pragma unroll
    for (int tg = 0; tg < 8; ++tg) acc[tg] = (floatx4){0.f, 0.f, 0.f, 0.f};
    #pragma unroll
    for (int tg = 0; tg < 8; ++tg) {
      acc[tg] = __builtin_amdgcn_mfma_f32_16x16x32_bf16(WF[tg][0], BF0, acc[tg], 0, 0, 0);
      acc[tg] = __builtin_amdgcn_mfma_f32_16x16x32_bf16(WF[tg][1], BF1, acc[tg], 0, 0, 0);
      acc[tg] = __builtin_amdgcn_mfma_f32_16x16x32_bf16(WF[tg][2], BF2, acc[tg], 0, 0, 0);
      acc[tg] = __builtin_amdgcn_mfma_f32_16x16x32_bf16(WF[tg][3], BF3, acc[tg], 0, 0, 0);
    }

    uint2* pf = pregS + (size_t)(gr*gstride + rec)*512 + (c + 16*kw);
    #pragma unroll
    for (int tg = 0; tg < 8; ++tg)
      pf[tg*64] = make_uint2(pkh(acc[tg][0]+bias[tg].x, acc[tg][1]+bias[tg].y),
                             pkh(acc[tg][2]+bias[tg].z, acc[tg][3]+bias[tg].w));

    uint2* mx2 = mxS + (size_t)(gr*gstride + rec)*256;
    mx2[(2*kw+0)*16 + c] = make_uint2(pkh(fa0.x,fa0.y), pkh(fa0.z,fa0.w));
    mx2[(2*kw+1)*16 + c] = make_uint2(pkh(fa1.x,fa1.y), pkh(fa1.z,fa1.w));
    mx2[(8+2*kw)*16 + c] = make_uint2(pkh(fb0.x,fb0.y), pkh(fb0.z,fb0.w));
    mx2[(9+2*kw)*16 + c] = make_uint2(pkh(fb1.x,fb1.y), pkh(fb1.z,fb1.w));

    float4* m14 = (float4*)m1S + (size_t)(gr*gstride + rec)*256;
    m14[(2*kw+0)*16 + c] = make_float4(1.f-ma0.x, 1.f-ma0.y, 1.f-ma0.z, 1.f-ma0.w);
    m14[(2*kw+1)*16 + c] = make_float4(1.f-ma1.x, 1.f-ma1.y, 1.f-ma1.z, 1.f-ma1.w);
    m14[(8+2*kw)*16 + c] = make_float4(1.f-mb0.x, 1.f-mb0.y, 1.f-mb0.z, 1.f-mb0.w);
    m14[(9+2*kw)*16 + c] = make_float4(1.f-mb1.x, 1.f-mb1.y, 1.f-mb1.z, 1.f-mb1.w);
  }
}

// ============ G2: gamma f16 (R11-proven, unchanged) ============
__global__ __launch_bounds__(256) void g2_gam(
    const float* __restrict__ deltas, const float* __restrict__ W_decay,
    const float* __restrict__ b_decay, float* __restrict__ gamS, int gstride)
{
  const int tid = threadIdx.x, wv = tid >> 6, l = tid & 63;
  const int c = l & 15, kw = l >> 4;
  const int tch = blockIdx.x, gr = blockIdx.y;
  const int tbase = tch * 8;

  short8 AF[2][2];
  #pragma unroll
  for (int jt = 0; jt < 2; ++jt)
    #pragma unroll
    for (int kc = 0; kc < 2; ++kc)
      AF[jt][kc] = mkfrag(W_decay + (size_t)(16*jt + c)*64 + 32*kc + 8*kw);
  float4 bd0 = *(const float4*)(b_decay + 4*kw);
  float4 bd1 = *(const float4*)(b_decay + 16 + 4*kw);

  #pragma unroll 1
  for (int tt = 0; tt < 2; ++tt) {
    const int rec = tbase + wv*2 + tt;
    const float* dr = deltas + ((size_t)(gr*16 + c)*2048 + rec)*64;
    float4 da0 = *(const float4*)(dr + 8*kw),      da1 = *(const float4*)(dr + 8*kw + 4);
    float4 db0 = *(const float4*)(dr + 32 + 8*kw), db1 = *(const float4*)(dr + 32 + 8*kw + 4);
    short8 B0 = pk8(da0, da1), B1 = pk8(db0, db1);
    floatx4 zz = (floatx4){0.f, 0.f, 0.f, 0.f};
    floatx4 a0 = __builtin_amdgcn_mfma_f32_16x16x32_bf16(AF[0][0], B0, zz, 0, 0, 0);
    a0 = __builtin_amdgcn_mfma_f32_16x16x32_bf16(AF[0][1], B1, a0, 0, 0, 0);
    floatx4 a1 = __builtin_amdgcn_mfma_f32_16x16x32_bf16(AF[1][0], B0, zz, 0, 0, 0);
    a1 = __builtin_amdgcn_mfma_f32_16x16x32_bf16(AF[1][1], B1, a1, 0, 0, 0);
    float g0 = __builtin_amdgcn_exp2f(-fmaxf(a0[0]+bd0.x, 0.f) * L2E);
    float g1 = __builtin_amdgcn_exp2f(-fmaxf(a0[1]+bd0.y, 0.f) * L2E);
    float g2 = __builtin_amdgcn_exp2f(-fmaxf(a0[2]+bd0.z, 0.f) * L2E);
    float g3 = __builtin_amdgcn_exp2f(-fmaxf(a0[3]+bd0.w, 0.f) * L2E);
    float h0 = __builtin_amdgcn_exp2f(-fmaxf(a1[0]+bd1.x, 0.f) * L2E);
    float h1 = __builtin_amdgcn_exp2f(-fmaxf(a1[1]+bd1.y, 0.f) * L2E);
    float h2 = __builtin_amdgcn_exp2f(-fmaxf(a1[2]+bd1.z, 0.f) * L2E);
    float h3 = __builtin_amdgcn_exp2f(-fmaxf(a1[3]+bd1.w, 0.f) * L2E);
    uintx4 o = (uintx4){pkh(g0, g1), pkh(g2, g3), pkh(h0, h1), pkh(h2, h3)};
    ((uintx4*)gamS)[(size_t)(gr*gstride + rec)*64 + c + 16*kw] = o;
  }
}

// ============ P14: 2-wave split, glds ring (counted vmcnt), stores hd only ============
#define PW(GI, GF, GG, GO, CC, HH) do { \
  float _si = __builtin_amdgcn_rcpf(1.f + __builtin_amdgcn_exp2f((GI) * -L2E)); \
  float _sf = __builtin_amdgcn_rcpf(1.f + __builtin_amdgcn_exp2f((GF) * -L2E)); \
  float _so = __builtin_amdgcn_rcpf(1.f + __builtin_amdgcn_exp2f((GO) * -L2E)); \
  float _tg = 1.f - 2.f*__builtin_amdgcn_rcpf(1.f + __builtin_amdgcn_exp2f((GG) * (2.f*L2E))); \
  float _cn = fmaf(_sf, (CC), _si*_tg); \
  float _tc = 1.f - 2.f*__builtin_amdgcn_rcpf(1.f + __builtin_amdgcn_exp2f(_cn * (2.f*L2E))); \
  (CC) = _cn; (HH) = _so * _tc; \
} while (0)

#define SLOTB 9216   // preg 4096 | m1 4096 | gam 1024

__global__ __launch_bounds__(128, 1) void p14_rnn(
    const float* __restrict__ W_hh, const float* __restrict__ W_reg,
    const float* __restrict__ W_ih, const float* __restrict__ b_reg,
    const float* __restrict__ W_out, const float* __restrict__ b_out,
    const char* __restrict__ pregS, const char* __restrict__ gamS,
    const char* __restrict__ m1S, char* __restrict__ hdG,
    float* __restrict__ y, int gstride)
{
  const int tid = threadIdx.x, gr = blockIdx.x;
  const int wid = tid >> 6, l = tid & 63;
  const int b = l & 15, w = l >> 4;

  __shared__ __align__(16) char ring[4 * SLOTB];
  __shared__ __align__(16) char hdB[2 * 1536];
  __shared__ float yL[2][16][2];

  short8 WhhA[4], WxcA0[4], WxcA1[4], WregA[4];
  #pragma unroll
  for (int tt = 0; tt < 4; ++tt) {
    const int tg = 2*tt + wid;
    WhhA[tt]  = mkfrag(W_hh + (size_t)(16*tg + b)*32 + 8*w);
    WxcA0[tt] = mkfrag(W_ih + (size_t)(16*tg + b)*128 + 8*w);
    WxcA1[tt] = mkfrag(W_ih + (size_t)(16*tg + b)*128 + 32 + 8*w);
    WregA[tt] = mkfrag(W_reg + (size_t)(16*tt + b)*32 + 8*w);
  }
  floatx4 brC[4];
  #pragma unroll
  for (int t = 0; t < 4; ++t) {
    float4 v = *(const float4*)(b_reg + 16*t + 4*w);
    brC[t] = (floatx4){v.x, v.y, v.z, v.w};
  }

  float4 h = make_float4(0.f, 0.f, 0.f, 0.f);
  float4 cv = make_float4(0.f, 0.f, 0.f, 0.f);

  // glds source bases (include lane offset l*16)
  const char* pregB = pregS + (size_t)gr*gstride*4096 + (size_t)l*16;
  const char* gamGB = gamS  + (size_t)gr*gstride*1024 + (size_t)l*16;
  const char* m1B   = m1S   + (size_t)gr*gstride*4096 + (size_t)l*16;
  char* hdP = hdG + (size_t)gr*gstride*1024 + b*64 + wid*32 + w*8;

  auto PREFL = [&](int rec, int slot) {
    char* sb = ring + slot * SLOTB;
    const char* pb = pregB + (size_t)rec*4096;
    const char* mb = m1B   + (size_t)rec*4096;
    if (wid == 0) {
      GLDS16(pb,        sb);
      GLDS16(pb + 1024, sb + 1024);
      GLDS16(pb + 2048, sb + 2048);
      GLDS16(pb + 3072, sb + 3072);
      GLDS16(mb,        sb + 4096);
    } else {
      GLDS16(mb + 1024, sb + 5120);
      GLDS16(mb + 2048, sb + 6144);
      GLDS16(mb + 3072, sb + 7168);
      GLDS16(gamGB + (size_t)rec*1024, sb + 8192);
    }
  };

  uint2 PRr[2][4], GMr[2];
  float4 M1r[2][4];

  auto LDSRD = [&](int slot, int j) {
    const char* sb = ring + slot * SLOTB;
    #pragma unroll
    for (int tt = 0; tt < 4; ++tt)
      PRr[j][tt] = *(const uint2*)(sb + ((2*tt + wid)*64 + l)*8);
    GMr[j] = *(const uint2*)(sb + 8192 + (b + 16*w)*16 + wid*8);
    #pragma unroll
    for (int t = 0; t < 4; ++t)
      M1r[j][t] = *(const float4*)(sb + 4096 + ((4*t + w)*16 + b)*16);
  };

  auto BODY = [&](int s, int j, int par) {
    PREFL(s + 3, (s + 3) & 3);
    // drain glds(s+1): allow 2 steps of glds + 2 hd stores in flight
    if (wid == 0) asm volatile("s_waitcnt vmcnt(12)" ::: "memory");
    else          asm volatile("s_waitcnt vmcnt(10)" ::: "memory");

    float2 g01 = uph(GMr[j].x), g23 = uph(GMr[j].y);
    float4 hd = make_float4(h.x*g01.x, h.y*g01.y, h.z*g23.x, h.w*g23.y);
    uint32_t K0 = pkbf(hd.x, hd.y), K1 = pkbf(hd.z, hd.w);
    *(uint2*)hdP = make_uint2(K0, K1);
    hdP += 1024;
    *(uint2*)(hdB + par*1536 + b*96 + wid*32 + w*8) = make_uint2(K0, K1);
    asm volatile("s_waitcnt lgkmcnt(0)" ::: "memory");
    __builtin_amdgcn_s_barrier();
    asm volatile("" ::: "memory");
    short8 Bhd = *(const short8*)(hdB + par*1536 + b*96 + w*16);
    LDSRD((s + 1) & 3, j ^ 1);

    floatx4 uu[4];
    #pragma unroll
    for (int t = 0; t < 4; ++t)
      uu[t] = __builtin_amdgcn_mfma_f32_16x16x32_bf16(WregA[t], Bhd, brC[t], 0, 0, 0);
    floatx4 ga[4];
    #pragma unroll
    for (int tt = 0; tt < 4; ++tt) {
      float2 p01 = uph(PRr[j][tt].x), p23 = uph(PRr[j][tt].y);
      floatx4 ci = {p01.x, p01.y, p23.x, p23.y};
      ga[tt] = __builtin_amdgcn_mfma_f32_16x16x32_bf16(WhhA[tt], Bhd, ci, 0, 0, 0);
    }

    uint32_t U[8];
    #pragma unroll
    for (int t = 0; t < 4; ++t) {
      float4 m1v = M1r[j][t];
      float v0 = m1v.x*uu[t][0], v1 = m1v.y*uu[t][1];
      float v2 = m1v.z*uu[t][2], v3 = m1v.w*uu[t][3];
      U[2*t]   = pkbf(v0, v1);
      U[2*t+1] = pkbf(v2, v3);
    }
    SWAP32(U[0], U[2]); SWAP32(U[1], U[3]);
    SWAP16(U[0], U[2]); SWAP16(U[1], U[3]);
    short8 Bv0 = u4s8(U[0], U[1], U[2], U[3]);
    SWAP32(U[4], U[6]); SWAP32(U[5], U[7]);
    SWAP16(U[4], U[6]); SWAP16(U[5], U[7]);
    short8 Bv1 = u4s8(U[4], U[5], U[6], U[7]);

    #pragma unroll
    for (int tt = 0; tt < 4; ++tt)
      ga[tt] = __builtin_amdgcn_mfma_f32_16x16x32_bf16(WxcA0[tt], Bv0, ga[tt], 0, 0, 0);
    #pragma unroll
    for (int tt = 0; tt < 4; ++tt)
      ga[tt] = __builtin_amdgcn_mfma_f32_16x16x32_bf16(WxcA1[tt], Bv1, ga[tt], 0, 0, 0);

    PW(ga[0][0], ga[1][0], ga[2][0], ga[3][0], cv.x, h.x);
    PW(ga[0][1], ga[1][1], ga[2][1], ga[3][1], cv.y, h.y);
    PW(ga[0][2], ga[1][2], ga[2][2], ga[3][2], cv.z, h.z);
    PW(ga[0][3], ga[1][3], ga[2][3], ga[3][3], cv.w, h.w);
  };

  // prologue: fill slots 0..2, drain all, cross-wave sync, read step 0
  PREFL(0, 0); PREFL(1, 1); PREFL(2, 2);
  asm volatile("s_waitcnt vmcnt(0)" ::: "memory");
  __builtin_amdgcn_s_barrier();
  asm volatile("" ::: "memory");
  LDSRD(0, 0);

  #pragma unroll 1
  for (int s = 0; s < 2048; s += 2) {
    BODY(s, 0, 0);
    BODY(s + 1, 1, 1);
  }

  // y head
  {
    auto d4 = [](float4 a, float4 bb) {
      return fmaf(a.x, bb.x, fmaf(a.y, bb.y, fmaf(a.z, bb.z, a.w*bb.w)));
    };
    float4 wo0 = *(const float4*)(W_out + wid*16 + 4*w);
    float4 wo1 = *(const float4*)(W_out + 32 + wid*16 + 4*w);
    float p0 = d4(h, wo0);
    float p1 = d4(h, wo1);
    p0 += __shfl_xor(p0, 16); p0 += __shfl_xor(p0, 32);
    p1 += __shfl_xor(p1, 16); p1 += __shfl_xor(p1, 32);
    if (l < 16) { yL[wid][l][0] = p0; yL[wid][l][1] = p1; }
    asm volatile("s_waitcnt lgkmcnt(0)" ::: "memory");
    __builtin_amdgcn_s_barrier();
    asm volatile("" ::: "memory");
    if (wid == 0 && l < 16) {
      y[(gr*16 + l)*2 + 0] = yL[0][l][0] + yL[1][l][0] + b_out[0];
      y[(gr*16 + l)*2 + 1] = yL[0][l][1] + yL[1][l][1] + b_out[1];
    }
  }
}

// ============ P13_POST: imp = mx + m1 * (W_reg·hd + b_reg), fully parallel ============
__global__ __launch_bounds__(256) void p13_post(
    const float* __restrict__ W_reg, const float* __restrict__ b_reg,
    const char* __restrict__ hdG, const uint2* __restrict__ mxS,
    const float* __restrict__ m1S, float* __restrict__ imp, int gstride)
{
  const int tid = threadIdx.x, wv = tid >> 6, l = tid & 63;
  const int c = l & 15, kw = l >> 4;
  const int tch = blockIdx.x, gr = blockIdx.y;
  const int tbase = tch * 8;

  short8 WA[4];
  #pragma unroll
  for (int t = 0; t < 4; ++t)
    WA[t] = mkfrag(W_reg + (size_t)(16*t + c)*32 + 8*kw);
  floatx4 brC[4];
  #pragma unroll
  for (int t = 0; t < 4; ++t) {
    float4 v = *(const float4*)(b_reg + 16*t + 4*kw);
    brC[t] = (floatx4){v.x, v.y, v.z, v.w};
  }

  #pragma unroll 1
  for (int tt = 0; tt < 2; ++tt) {
    const int rec = tbase + wv*2 + tt;
    short8 Bhd = *(const short8*)(hdG + (size_t)(gr*gstride + rec)*1024 + c*64 + kw*16);
    floatx4 uu[4];
    #pragma unroll
    for (int t = 0; t < 4; ++t)
      uu[t] = __builtin_amdgcn_mfma_f32_16x16x32_bf16(WA[t], Bhd, brC[t], 0, 0, 0);

    float* dst = imp + ((size_t)(gr*16 + c)*2048 + rec)*64 + 4*kw;
    #pragma unroll
    for (int t = 0; t < 4; ++t) {
      float4 m1v = ((const float4*)m1S)[(size_t)(gr*gstride + rec)*256 + (4*t + kw)*16 + c];
      uint2 mxv = mxS[(size_t)(gr*gstride + rec)*256 + (4*t + kw)*16 + c];
      float2 mxa = uph(mxv.x), mxb = uph(mxv.y);
      *(float4*)(dst + 16*t) = make_float4(
          fmaf(m1v.x, uu[t][0], mxa.x), fmaf(m1v.y, uu[t][1], mxa.y),
          fmaf(m1v.z, uu[t][2], mxb.x), fmaf(m1v.w, uu[t][3], mxb.y));
    }
  }
}

extern "C" void kernel_launch(void* const* d_in, const int* in_sizes, int n_in,
                              void* d_out, int out_size, void* d_ws, size_t ws_size,
                              hipStream_t stream) {
  (void)in_sizes; (void)n_in; (void)out_size; (void)ws_size;
  const float* values  = (const float*)d_in[0];
  const float* masks   = (const float*)d_in[1];
  const float* deltas  = (const float*)d_in[2];
  const float* W_decay = (const float*)d_in[3];
  const float* b_decay = (const float*)d_in[4];
  const float* W_reg   = (const float*)d_in[5];
  const float* b_reg   = (const float*)d_in[6];
  const float* W_ih    = (const float*)d_in[7];
  const float* b_ih    = (const float*)d_in[8];
  const float* W_hh    = (const float*)d_in[9];
  const float* b_hh    = (const float*)d_in[10];
  const float* W_out   = (const float*)d_in[11];
  const float* b_out   = (const float*)d_in[12];
  float* y   = (float*)d_out;
  float* imp = (float*)d_out + 512;   // outputs: y [256,2] then imputations [256,2048,64]

  const int gstride = 2056;           // +8 pad for unconditional tail prefetch
  char* pregS = (char*)d_ws;                                   // 16*gstride*4096 B
  char* gamS  = pregS + (size_t)16*gstride*4096;               // 16*gstride*1024 B
  char* mxS   = gamS  + (size_t)16*gstride*1024;               // 16*gstride*2048 B
  char* m1S   = mxS   + (size_t)16*gstride*2048;               // 16*gstride*4096 B
  char* hdG   = m1S   + (size_t)16*gstride*4096;               // 16*gstride*1024 B

  hipLaunchKernelGGL(g1_pre, dim3(256, 16), dim3(256), 0, stream,
                     values, masks, W_ih, b_ih, b_hh,
                     (uint2*)pregS, (uint2*)mxS, (float*)m1S, gstride);
  hipLaunchKernelGGL(g2_gam, dim3(256, 16), dim3(256), 0, stream,
                     deltas, W_decay, b_decay, (float*)gamS, gstride);
  hipLaunchKernelGGL(p14_rnn, dim3(16), dim3(128), 0, stream,
                     W_hh, W_reg, W_ih, b_reg, W_out, b_out,
                     pregS, gamS, m1S, hdG, y, gstride);
  hipLaunchKernelGGL(p13_post, dim3(256, 16), dim3(256), 0, stream,
                     W_reg, b_reg, hdG, (const uint2*)mxS, (const float*)m1S,
                     imp, gstride);
}

// Round 15
// 1926.427 us; speedup vs baseline: 1.2899x; 1.2899x over previous
//
#include <hip/hip_runtime.h>
#include <stdint.h>

#define L2E 1.4426950408889634f

typedef __attribute__((ext_vector_type(8))) short short8;
typedef __attribute__((ext_vector_type(4))) float floatx4;
typedef __attribute__((ext_vector_type(4))) unsigned int uintx4;
typedef __attribute__((ext_vector_type(2))) _Float16 half2v;

__device__ __forceinline__ uint32_t pkbf(float lo, float hi) {
  uint32_t r;
  asm("v_cvt_pk_bf16_f32 %0, %1, %2" : "=v"(r) : "v"(lo), "v"(hi));
  return r;
}
__device__ __forceinline__ uint32_t pkh(float lo, float hi) {
  uint32_t r;
  asm("v_cvt_pkrtz_f16_f32 %0, %1, %2" : "=v"(r) : "v"(lo), "v"(hi));
  return r;
}
__device__ __forceinline__ float2 uph(uint32_t u) {
  union { uint32_t u; half2v h; } z; z.u = u;
  return make_float2((float)z.h.x, (float)z.h.y);
}
__device__ __forceinline__ short8 mkfrag(const float* p) {
  float4 a = *(const float4*)p;
  float4 b = *(const float4*)(p + 4);
  union { uint32_t u[4]; short8 s; } z;
  z.u[0] = pkbf(a.x, a.y); z.u[1] = pkbf(a.z, a.w);
  z.u[2] = pkbf(b.x, b.y); z.u[3] = pkbf(b.z, b.w);
  return z.s;
}
__device__ __forceinline__ short8 pk8(float4 a, float4 b) {
  union { uint32_t u[4]; short8 s; } z;
  z.u[0] = pkbf(a.x, a.y); z.u[1] = pkbf(a.z, a.w);
  z.u[2] = pkbf(b.x, b.y); z.u[3] = pkbf(b.z, b.w);
  return z.s;
}
__device__ __forceinline__ short8 u4s8(uint32_t a, uint32_t b, uint32_t c, uint32_t d) {
  union { uint32_t u[4]; short8 s; } z;
  z.u[0] = a; z.u[1] = b; z.u[2] = c; z.u[3] = d;
  return z.s;
}

#define SWAP32(a, b) asm("v_permlane32_swap_b32 %0, %1" : "+v"(a), "+v"(b))
#define SWAP16(a, b) asm("v_permlane16_swap_b32 %0, %1" : "+v"(a), "+v"(b))

// ============ G1: preg f16 + mx f16 / m1 f32 (R13 layouts, UNCHANGED) ============
__global__ __launch_bounds__(256) void g1_pre(
    const float* __restrict__ values, const float* __restrict__ masks,
    const float* __restrict__ W_ih, const float* __restrict__ b_ih,
    const float* __restrict__ b_hh, uint2* __restrict__ pregS,
    uint2* __restrict__ mxS, float* __restrict__ m1S, int gstride)
{
  const int tid = threadIdx.x, wv = tid >> 6, l = tid & 63;
  const int c = l & 15, kw = l >> 4;
  const int tch = blockIdx.x, gr = blockIdx.y;
  const int tbase = tch * 8;

  short8 WF[8][4];
  #pragma unroll
  for (int tg = 0; tg < 8; ++tg)
    #pragma unroll
    for (int kc = 0; kc < 4; ++kc)
      WF[tg][kc] = mkfrag(W_ih + (size_t)(16*tg + c)*128 + 32*kc + 8*kw);

  float4 bias[8];
  #pragma unroll
  for (int tg = 0; tg < 8; ++tg) {
    float4 bi = *(const float4*)(b_ih + 16*tg + 4*kw);
    float4 bh = *(const float4*)(b_hh + 16*tg + 4*kw);
    bias[tg] = make_float4(bi.x+bh.x, bi.y+bh.y, bi.z+bh.z, bi.w+bh.w);
  }

  #pragma unroll 1
  for (int tt = 0; tt < 2; ++tt) {
    const int rec = tbase + wv*2 + tt;
    const size_t ibase = ((size_t)(gr*16 + c)*2048 + rec)*64;
    const float* xr = values + ibase;
    const float* mr = masks + ibase;
    float4 xa0 = *(const float4*)(xr + 8*kw),      xa1 = *(const float4*)(xr + 8*kw + 4);
    float4 xb0 = *(const float4*)(xr + 32 + 8*kw), xb1 = *(const float4*)(xr + 32 + 8*kw + 4);
    float4 ma0 = *(const float4*)(mr + 8*kw),      ma1 = *(const float4*)(mr + 8*kw + 4);
    float4 mb0 = *(const float4*)(mr + 32 + 8*kw), mb1 = *(const float4*)(mr + 32 + 8*kw + 4);
    float4 fa0 = make_float4(xa0.x*ma0.x, xa0.y*ma0.y, xa0.z*ma0.z, xa0.w*ma0.w);
    float4 fa1 = make_float4(xa1.x*ma1.x, xa1.y*ma1.y, xa1.z*ma1.z, xa1.w*ma1.w);
    float4 fb0 = make_float4(xb0.x*mb0.x, xb0.y*mb0.y, xb0.z*mb0.z, xb0.w*mb0.w);
    float4 fb1 = make_float4(xb1.x*mb1.x, xb1.y*mb1.y, xb1.z*mb1.z, xb1.w*mb1.w);

    short8 BF0 = pk8(fa0, fa1), BF1 = pk8(fb0, fb1);
    short8 BF2 = pk8(ma0, ma1), BF3 = pk8(mb0, mb1);

    floatx4 acc[8];
    #pragma unroll
    for (int tg = 0; tg < 8; ++tg) acc[tg] = (floatx4){0.f, 0.f, 0.f, 0.f};
    #pragma unroll
    for (int tg = 0; tg < 8; ++tg) {
      acc[tg] = __builtin_amdgcn_mfma_f32_16x16x32_bf16(WF[tg][0], BF0, acc[tg], 0, 0, 0);
      acc[tg] = __builtin_amdgcn_mfma_f32_16x16x32_bf16(WF[tg][1], BF1, acc[tg], 0, 0, 0);
      acc[tg] = __builtin_amdgcn_mfma_f32_16x16x32_bf16(WF[tg][2], BF2, acc[tg], 0, 0, 0);
      acc[tg] = __builtin_amdgcn_mfma_f32_16x16x32_bf16(WF[tg][3], BF3, acc[tg], 0, 0, 0);
    }

    uint2* pf = pregS + (size_t)(gr*gstride + rec)*512 + (c + 16*kw);
    #pragma unroll
    for (int tg = 0; tg < 8; ++tg)
      pf[tg*64] = make_uint2(pkh(acc[tg][0]+bias[tg].x, acc[tg][1]+bias[tg].y),
                             pkh(acc[tg][2]+bias[tg].z, acc[tg][3]+bias[tg].w));

    uint2* mx2 = mxS + (size_t)(gr*gstride + rec)*256;
    mx2[(2*kw+0)*16 + c] = make_uint2(pkh(fa0.x,fa0.y), pkh(fa0.z,fa0.w));
    mx2[(2*kw+1)*16 + c] = make_uint2(pkh(fa1.x,fa1.y), pkh(fa1.z,fa1.w));
    mx2[(8+2*kw)*16 + c] = make_uint2(pkh(fb0.x,fb0.y), pkh(fb0.z,fb0.w));
    mx2[(9+2*kw)*16 + c] = make_uint2(pkh(fb1.x,fb1.y), pkh(fb1.z,fb1.w));

    float4* m14 = (float4*)m1S + (size_t)(gr*gstride + rec)*256;
    m14[(2*kw+0)*16 + c] = make_float4(1.f-ma0.x, 1.f-ma0.y, 1.f-ma0.z, 1.f-ma0.w);
    m14[(2*kw+1)*16 + c] = make_float4(1.f-ma1.x, 1.f-ma1.y, 1.f-ma1.z, 1.f-ma1.w);
    m14[(8+2*kw)*16 + c] = make_float4(1.f-mb0.x, 1.f-mb0.y, 1.f-mb0.z, 1.f-mb0.w);
    m14[(9+2*kw)*16 + c] = make_float4(1.f-mb1.x, 1.f-mb1.y, 1.f-mb1.z, 1.f-mb1.w);
  }
}

// ============ G2: gamma f16 (R13-proven, UNCHANGED) ============
__global__ __launch_bounds__(256) void g2_gam(
    const float* __restrict__ deltas, const float* __restrict__ W_decay,
    const float* __restrict__ b_decay, float* __restrict__ gamS, int gstride)
{
  const int tid = threadIdx.x, wv = tid >> 6, l = tid & 63;
  const int c = l & 15, kw = l >> 4;
  const int tch = blockIdx.x, gr = blockIdx.y;
  const int tbase = tch * 8;

  short8 AF[2][2];
  #pragma unroll
  for (int jt = 0; jt < 2; ++jt)
    #pragma unroll
    for (int kc = 0; kc < 2; ++kc)
      AF[jt][kc] = mkfrag(W_decay + (size_t)(16*jt + c)*64 + 32*kc + 8*kw);
  float4 bd0 = *(const float4*)(b_decay + 4*kw);
  float4 bd1 = *(const float4*)(b_decay + 16 + 4*kw);

  #pragma unroll 1
  for (int tt = 0; tt < 2; ++tt) {
    const int rec = tbase + wv*2 + tt;
    const float* dr = deltas + ((size_t)(gr*16 + c)*2048 + rec)*64;
    float4 da0 = *(const float4*)(dr + 8*kw),      da1 = *(const float4*)(dr + 8*kw + 4);
    float4 db0 = *(const float4*)(dr + 32 + 8*kw), db1 = *(const float4*)(dr + 32 + 8*kw + 4);
    short8 B0 = pk8(da0, da1), B1 = pk8(db0, db1);
    floatx4 zz = (floatx4){0.f, 0.f, 0.f, 0.f};
    floatx4 a0 = __builtin_amdgcn_mfma_f32_16x16x32_bf16(AF[0][0], B0, zz, 0, 0, 0);
    a0 = __builtin_amdgcn_mfma_f32_16x16x32_bf16(AF[0][1], B1, a0, 0, 0, 0);
    floatx4 a1 = __builtin_amdgcn_mfma_f32_16x16x32_bf16(AF[1][0], B0, zz, 0, 0, 0);
    a1 = __builtin_amdgcn_mfma_f32_16x16x32_bf16(AF[1][1], B1, a1, 0, 0, 0);
    float g0 = __builtin_amdgcn_exp2f(-fmaxf(a0[0]+bd0.x, 0.f) * L2E);
    float g1 = __builtin_amdgcn_exp2f(-fmaxf(a0[1]+bd0.y, 0.f) * L2E);
    float g2 = __builtin_amdgcn_exp2f(-fmaxf(a0[2]+bd0.z, 0.f) * L2E);
    float g3 = __builtin_amdgcn_exp2f(-fmaxf(a0[3]+bd0.w, 0.f) * L2E);
    float h0 = __builtin_amdgcn_exp2f(-fmaxf(a1[0]+bd1.x, 0.f) * L2E);
    float h1 = __builtin_amdgcn_exp2f(-fmaxf(a1[1]+bd1.y, 0.f) * L2E);
    float h2 = __builtin_amdgcn_exp2f(-fmaxf(a1[2]+bd1.z, 0.f) * L2E);
    float h3 = __builtin_amdgcn_exp2f(-fmaxf(a1[3]+bd1.w, 0.f) * L2E);
    uintx4 o = (uintx4){pkh(g0, g1), pkh(g2, g3), pkh(h0, h1), pkh(h2, h3)};
    ((uintx4*)gamS)[(size_t)(gr*gstride + rec)*64 + c + 16*kw] = o;
  }
}

// ============ P15: R13 recurrence split into col-halves (32 blocks x 2 waves) ============
// block = 2*gr + half; owns batch cols bb = half*8 + (b&7) of group gr's records.
// Lanes b>=8 duplicate lanes b-8 (exact copies) to fill MFMA tiles; stores gated to b<8.
#define PW(GI, GF, GG, GO, CC, HH) do { \
  float _si = __builtin_amdgcn_rcpf(1.f + __builtin_amdgcn_exp2f((GI) * -L2E)); \
  float _sf = __builtin_amdgcn_rcpf(1.f + __builtin_amdgcn_exp2f((GF) * -L2E)); \
  float _so = __builtin_amdgcn_rcpf(1.f + __builtin_amdgcn_exp2f((GO) * -L2E)); \
  float _tg = 1.f - 2.f*__builtin_amdgcn_rcpf(1.f + __builtin_amdgcn_exp2f((GG) * (2.f*L2E))); \
  float _cn = fmaf(_sf, (CC), _si*_tg); \
  float _tc = 1.f - 2.f*__builtin_amdgcn_rcpf(1.f + __builtin_amdgcn_exp2f(_cn * (2.f*L2E))); \
  (CC) = _cn; (HH) = _so * _tc; \
} while (0)

__global__ __launch_bounds__(128, 1) void p15_rnn(
    const float* __restrict__ W_hh, const float* __restrict__ W_reg,
    const float* __restrict__ W_ih, const float* __restrict__ b_reg,
    const float* __restrict__ W_out, const float* __restrict__ b_out,
    const uint2* __restrict__ pregS, const char* __restrict__ gamS,
    const float* __restrict__ m1S, char* __restrict__ hdG,
    float* __restrict__ y, int gstride)
{
  const int tid = threadIdx.x;
  const int gr = blockIdx.x >> 1, half = blockIdx.x & 1;
  const int wid = tid >> 6, l = tid & 63;
  const int b = l & 15, w = l >> 4;
  const int bb = (b & 7) | (half << 3);   // this block's absolute column

  __shared__ __align__(16) char hdB[2 * 1536];
  __shared__ float yL[2][8][2];

  short8 WhhA[4], WxcA0[4], WxcA1[4], WregA[4];
  #pragma unroll
  for (int tt = 0; tt < 4; ++tt) {
    const int tg = 2*tt + wid;
    WhhA[tt]  = mkfrag(W_hh + (size_t)(16*tg + b)*32 + 8*w);
    WxcA0[tt] = mkfrag(W_ih + (size_t)(16*tg + b)*128 + 8*w);
    WxcA1[tt] = mkfrag(W_ih + (size_t)(16*tg + b)*128 + 32 + 8*w);
    WregA[tt] = mkfrag(W_reg + (size_t)(16*tt + b)*32 + 8*w);
  }
  floatx4 brC[4];
  #pragma unroll
  for (int t = 0; t < 4; ++t) {
    float4 v = *(const float4*)(b_reg + 16*t + 4*w);
    brC[t] = (floatx4){v.x, v.y, v.z, v.w};
  }

  float4 h = make_float4(0.f, 0.f, 0.f, 0.f);
  float4 cv = make_float4(0.f, 0.f, 0.f, 0.f);

  // stream bases use column bb (half-split of the shared 16-col records)
  const uint2* pPreg = pregS + (size_t)gr*gstride*512 + (bb + 16*w);
  const char*  gamB  = gamS + (size_t)gr*gstride*1024 + (size_t)(bb + 16*w)*16 + wid*8;
  const float4* pM1  = (const float4*)m1S + (size_t)gr*gstride*256;
  char* hdP = hdG + (size_t)gr*gstride*1024 + bb*64 + wid*32 + w*8;

  uint2 PR[2][4], GM[2];
  float4 M1r[2][4];

  auto PREF = [&](int s, int j) {
    #pragma unroll
    for (int tt = 0; tt < 4; ++tt) PR[j][tt] = pPreg[(size_t)s*512 + (2*tt + wid)*64];
    GM[j] = *(const uint2*)(gamB + (size_t)s*1024);
    #pragma unroll
    for (int t = 0; t < 4; ++t) M1r[j][t] = pM1[(size_t)s*256 + (4*t + w)*16 + bb];
  };

  auto BODY = [&](int j, int par) {
    float2 g01 = uph(GM[j].x), g23 = uph(GM[j].y);
    float4 hd = make_float4(h.x*g01.x, h.y*g01.y, h.z*g23.x, h.w*g23.y);
    uint32_t K0 = pkbf(hd.x, hd.y), K1 = pkbf(hd.z, hd.w);
    if (b < 8) *(uint2*)hdP = make_uint2(K0, K1);
    hdP += 1024;
    *(uint2*)(hdB + par*1536 + b*96 + wid*32 + w*8) = make_uint2(K0, K1);
    asm volatile("s_waitcnt lgkmcnt(0)" ::: "memory");
    __builtin_amdgcn_s_barrier();
    asm volatile("" ::: "memory");
    short8 Bhd = *(const short8*)(hdB + par*1536 + b*96 + w*16);

    floatx4 uu[4];
    #pragma unroll
    for (int t = 0; t < 4; ++t)
      uu[t] = __builtin_amdgcn_mfma_f32_16x16x32_bf16(WregA[t], Bhd, brC[t], 0, 0, 0);
    floatx4 ga[4];
    #pragma unroll
    for (int tt = 0; tt < 4; ++tt) {
      float2 p01 = uph(PR[j][tt].x), p23 = uph(PR[j][tt].y);
      floatx4 ci = {p01.x, p01.y, p23.x, p23.y};
      ga[tt] = __builtin_amdgcn_mfma_f32_16x16x32_bf16(WhhA[tt], Bhd, ci, 0, 0, 0);
    }

    uint32_t U[8];
    #pragma unroll
    for (int t = 0; t < 4; ++t) {
      float4 m1v = M1r[j][t];
      float v0 = m1v.x*uu[t][0], v1 = m1v.y*uu[t][1];
      float v2 = m1v.z*uu[t][2], v3 = m1v.w*uu[t][3];
      U[2*t]   = pkbf(v0, v1);
      U[2*t+1] = pkbf(v2, v3);
    }
    SWAP32(U[0], U[2]); SWAP32(U[1], U[3]);
    SWAP16(U[0], U[2]); SWAP16(U[1], U[3]);
    short8 Bv0 = u4s8(U[0], U[1], U[2], U[3]);
    SWAP32(U[4], U[6]); SWAP32(U[5], U[7]);
    SWAP16(U[4], U[6]); SWAP16(U[5], U[7]);
    short8 Bv1 = u4s8(U[4], U[5], U[6], U[7]);

    #pragma unroll
    for (int tt = 0; tt < 4; ++tt)
      ga[tt] = __builtin_amdgcn_mfma_f32_16x16x32_bf16(WxcA0[tt], Bv0, ga[tt], 0, 0, 0);
    #pragma unroll
    for (int tt = 0; tt < 4; ++tt)
      ga[tt] = __builtin_amdgcn_mfma_f32_16x16x32_bf16(WxcA1[tt], Bv1, ga[tt], 0, 0, 0);

    PW(ga[0][0], ga[1][0], ga[2][0], ga[3][0], cv.x, h.x);
    PW(ga[0][1], ga[1][1], ga[2][1], ga[3][1], cv.y, h.y);
    PW(ga[0][2], ga[1][2], ga[2][2], ga[3][2], cv.z, h.z);
    PW(ga[0][3], ga[1][3], ga[2][3], ga[3][3], cv.w, h.w);
  };

  PREF(0, 0); PREF(1, 1);
  #pragma unroll 1
  for (int s = 0; s < 2048; s += 2) {
    BODY(0, 0); PREF(s + 2, 0);
    BODY(1, 1); PREF(s + 3, 1);
  }

  // y head: reduce over w (shfl 16/32), cols bb, lanes l<8 (w=0)
  {
    auto d4 = [](float4 a, float4 bb_) {
      return fmaf(a.x, bb_.x, fmaf(a.y, bb_.y, fmaf(a.z, bb_.z, a.w*bb_.w)));
    };
    float4 wo0 = *(const float4*)(W_out + wid*16 + 4*w);
    float4 wo1 = *(const float4*)(W_out + 32 + wid*16 + 4*w);
    float p0 = d4(h, wo0);
    float p1 = d4(h, wo1);
    p0 += __shfl_xor(p0, 16); p0 += __shfl_xor(p0, 32);
    p1 += __shfl_xor(p1, 16); p1 += __shfl_xor(p1, 32);
    if (l < 8) { yL[wid][l][0] = p0; yL[wid][l][1] = p1; }
    asm volatile("s_waitcnt lgkmcnt(0)" ::: "memory");
    __builtin_amdgcn_s_barrier();
    asm volatile("" ::: "memory");
    if (wid == 0 && l < 8) {
      const int row = gr*16 + (l | (half << 3));
      y[row*2 + 0] = yL[0][l][0] + yL[1][l][0] + b_out[0];
      y[row*2 + 1] = yL[0][l][1] + yL[1][l][1] + b_out[1];
    }
  }
}

// ============ P13_POST: imp = mx + m1 * (W_reg·hd + b_reg) (R13-proven, UNCHANGED) ============
__global__ __launch_bounds__(256) void p13_post(
    const float* __restrict__ W_reg, const float* __restrict__ b_reg,
    const char* __restrict__ hdG, const uint2* __restrict__ mxS,
    const float* __restrict__ m1S, float* __restrict__ imp, int gstride)
{
  const int tid = threadIdx.x, wv = tid >> 6, l = tid & 63;
  const int c = l & 15, kw = l >> 4;
  const int tch = blockIdx.x, gr = blockIdx.y;
  const int tbase = tch * 8;

  short8 WA[4];
  #pragma unroll
  for (int t = 0; t < 4; ++t)
    WA[t] = mkfrag(W_reg + (size_t)(16*t + c)*32 + 8*kw);
  floatx4 brC[4];
  #pragma unroll
  for (int t = 0; t < 4; ++t) {
    float4 v = *(const float4*)(b_reg + 16*t + 4*kw);
    brC[t] = (floatx4){v.x, v.y, v.z, v.w};
  }

  #pragma unroll 1
  for (int tt = 0; tt < 2; ++tt) {
    const int rec = tbase + wv*2 + tt;
    short8 Bhd = *(const short8*)(hdG + (size_t)(gr*gstride + rec)*1024 + c*64 + kw*16);
    floatx4 uu[4];
    #pragma unroll
    for (int t = 0; t < 4; ++t)
      uu[t] = __builtin_amdgcn_mfma_f32_16x16x32_bf16(WA[t], Bhd, brC[t], 0, 0, 0);

    float* dst = imp + ((size_t)(gr*16 + c)*2048 + rec)*64 + 4*kw;
    #pragma unroll
    for (int t = 0; t < 4; ++t) {
      float4 m1v = ((const float4*)m1S)[(size_t)(gr*gstride + rec)*256 + (4*t + kw)*16 + c];
      uint2 mxv = mxS[(size_t)(gr*gstride + rec)*256 + (4*t + kw)*16 + c];
      float2 mxa = uph(mxv.x), mxb = uph(mxv.y);
      *(float4*)(dst + 16*t) = make_float4(
          fmaf(m1v.x, uu[t][0], mxa.x), fmaf(m1v.y, uu[t][1], mxa.y),
          fmaf(m1v.z, uu[t][2], mxb.x), fmaf(m1v.w, uu[t][3], mxb.y));
    }
  }
}

extern "C" void kernel_launch(void* const* d_in, const int* in_sizes, int n_in,
                              void* d_out, int out_size, void* d_ws, size_t ws_size,
                              hipStream_t stream) {
  (void)in_sizes; (void)n_in; (void)out_size; (void)ws_size;
  const float* values  = (const float*)d_in[0];
  const float* masks   = (const float*)d_in[1];
  const float* deltas  = (const float*)d_in[2];
  const float* W_decay = (const float*)d_in[3];
  const float* b_decay = (const float*)d_in[4];
  const float* W_reg   = (const float*)d_in[5];
  const float* b_reg   = (const float*)d_in[6];
  const float* W_ih    = (const float*)d_in[7];
  const float* b_ih    = (const float*)d_in[8];
  const float* W_hh    = (const float*)d_in[9];
  const float* b_hh    = (const float*)d_in[10];
  const float* W_out   = (const float*)d_in[11];
  const float* b_out   = (const float*)d_in[12];
  float* y   = (float*)d_out;
  float* imp = (float*)d_out + 512;   // outputs: y [256,2] then imputations [256,2048,64]

  const int gstride = 2056;           // +8 pad for unconditional tail prefetch
  char* pregS = (char*)d_ws;                                   // 16*gstride*4096 B
  char* gamS  = pregS + (size_t)16*gstride*4096;               // 16*gstride*1024 B
  char* mxS   = gamS  + (size_t)16*gstride*1024;               // 16*gstride*2048 B
  char* m1S   = mxS   + (size_t)16*gstride*2048;               // 16*gstride*4096 B
  char* hdG   = m1S   + (size_t)16*gstride*4096;               // 16*gstride*1024 B

  hipLaunchKernelGGL(g1_pre, dim3(256, 16), dim3(256), 0, stream,
                     values, masks, W_ih, b_ih, b_hh,
                     (uint2*)pregS, (uint2*)mxS, (float*)m1S, gstride);
  hipLaunchKernelGGL(g2_gam, dim3(256, 16), dim3(256), 0, stream,
                     deltas, W_decay, b_decay, (float*)gamS, gstride);
  hipLaunchKernelGGL(p15_rnn, dim3(32), dim3(128), 0, stream,
                     W_hh, W_reg, W_ih, b_reg, W_out, b_out,
                     (const uint2*)pregS, gamS, (const float*)m1S, hdG, y, gstride);
  hipLaunchKernelGGL(p13_post, dim3(256, 16), dim3(256), 0, stream,
                     W_reg, b_reg, hdG, (const uint2*)mxS, (const float*)m1S,
                     imp, gstride);
}

// Round 16
// 1762.389 us; speedup vs baseline: 1.4100x; 1.0931x over previous
//
#include <hip/hip_runtime.h>
#include <stdint.h>

#define L2E 1.4426950408889634f

typedef __attribute__((ext_vector_type(8))) short short8;
typedef __attribute__((ext_vector_type(4))) float floatx4;
typedef __attribute__((ext_vector_type(4))) unsigned int uintx4;
typedef __attribute__((ext_vector_type(2))) _Float16 half2v;

__device__ __forceinline__ uint32_t pkbf(float lo, float hi) {
  uint32_t r;
  asm("v_cvt_pk_bf16_f32 %0, %1, %2" : "=v"(r) : "v"(lo), "v"(hi));
  return r;
}
__device__ __forceinline__ uint32_t pkh(float lo, float hi) {
  uint32_t r;
  asm("v_cvt_pkrtz_f16_f32 %0, %1, %2" : "=v"(r) : "v"(lo), "v"(hi));
  return r;
}
__device__ __forceinline__ float2 uph(uint32_t u) {
  union { uint32_t u; half2v h; } z; z.u = u;
  return make_float2((float)z.h.x, (float)z.h.y);
}
__device__ __forceinline__ short8 mkfrag(const float* p) {
  float4 a = *(const float4*)p;
  float4 b = *(const float4*)(p + 4);
  union { uint32_t u[4]; short8 s; } z;
  z.u[0] = pkbf(a.x, a.y); z.u[1] = pkbf(a.z, a.w);
  z.u[2] = pkbf(b.x, b.y); z.u[3] = pkbf(b.z, b.w);
  return z.s;
}
__device__ __forceinline__ short8 pk8(float4 a, float4 b) {
  union { uint32_t u[4]; short8 s; } z;
  z.u[0] = pkbf(a.x, a.y); z.u[1] = pkbf(a.z, a.w);
  z.u[2] = pkbf(b.x, b.y); z.u[3] = pkbf(b.z, b.w);
  return z.s;
}
__device__ __forceinline__ short8 u4s8(uint32_t a, uint32_t b, uint32_t c, uint32_t d) {
  union { uint32_t u[4]; short8 s; } z;
  z.u[0] = a; z.u[1] = b; z.u[2] = c; z.u[3] = d;
  return z.s;
}

#define SWAP32(a, b) asm("v_permlane32_swap_b32 %0, %1" : "+v"(a), "+v"(b))
#define SWAP16(a, b) asm("v_permlane16_swap_b32 %0, %1" : "+v"(a), "+v"(b))

// ============ G1: preg f16 (R13 layout) + om bitmask (64b per row,step) ============
__global__ __launch_bounds__(256) void g1_pre(
    const float* __restrict__ values, const float* __restrict__ masks,
    const float* __restrict__ W_ih, const float* __restrict__ b_ih,
    const float* __restrict__ b_hh, uint2* __restrict__ pregS,
    unsigned char* __restrict__ omS, int gstride)
{
  const int tid = threadIdx.x, wv = tid >> 6, l = tid & 63;
  const int c = l & 15, kw = l >> 4;
  const int tch = blockIdx.x, gr = blockIdx.y;
  const int tbase = tch * 8;

  short8 WF[8][4];
  #pragma unroll
  for (int tg = 0; tg < 8; ++tg)
    #pragma unroll
    for (int kc = 0; kc < 4; ++kc)
      WF[tg][kc] = mkfrag(W_ih + (size_t)(16*tg + c)*128 + 32*kc + 8*kw);

  float4 bias[8];
  #pragma unroll
  for (int tg = 0; tg < 8; ++tg) {
    float4 bi = *(const float4*)(b_ih + 16*tg + 4*kw);
    float4 bh = *(const float4*)(b_hh + 16*tg + 4*kw);
    bias[tg] = make_float4(bi.x+bh.x, bi.y+bh.y, bi.z+bh.z, bi.w+bh.w);
  }

  #pragma unroll 1
  for (int tt = 0; tt < 2; ++tt) {
    const int rec = tbase + wv*2 + tt;
    const size_t ibase = ((size_t)(gr*16 + c)*2048 + rec)*64;
    const float* xr = values + ibase;
    const float* mr = masks + ibase;
    float4 xa0 = *(const float4*)(xr + 8*kw),      xa1 = *(const float4*)(xr + 8*kw + 4);
    float4 xb0 = *(const float4*)(xr + 32 + 8*kw), xb1 = *(const float4*)(xr + 32 + 8*kw + 4);
    float4 ma0 = *(const float4*)(mr + 8*kw),      ma1 = *(const float4*)(mr + 8*kw + 4);
    float4 mb0 = *(const float4*)(mr + 32 + 8*kw), mb1 = *(const float4*)(mr + 32 + 8*kw + 4);
    float4 fa0 = make_float4(xa0.x*ma0.x, xa0.y*ma0.y, xa0.z*ma0.z, xa0.w*ma0.w);
    float4 fa1 = make_float4(xa1.x*ma1.x, xa1.y*ma1.y, xa1.z*ma1.z, xa1.w*ma1.w);
    float4 fb0 = make_float4(xb0.x*mb0.x, xb0.y*mb0.y, xb0.z*mb0.z, xb0.w*mb0.w);
    float4 fb1 = make_float4(xb1.x*mb1.x, xb1.y*mb1.y, xb1.z*mb1.z, xb1.w*mb1.w);

    short8 BF0 = pk8(fa0, fa1), BF1 = pk8(fb0, fb1);
    short8 BF2 = pk8(ma0, ma1), BF3 = pk8(mb0, mb1);

    floatx4 acc[8];
    #pragma unroll
    for (int tg = 0; tg < 8; ++tg) acc[tg] = (floatx4){0.f, 0.f, 0.f, 0.f};
    #pragma unroll
    for (int tg = 0; tg < 8; ++tg) {
      acc[tg] = __builtin_amdgcn_mfma_f32_16x16x32_bf16(WF[tg][0], BF0, acc[tg], 0, 0, 0);
      acc[tg] = __builtin_amdgcn_mfma_f32_16x16x32_bf16(WF[tg][1], BF1, acc[tg], 0, 0, 0);
      acc[tg] = __builtin_amdgcn_mfma_f32_16x16x32_bf16(WF[tg][2], BF2, acc[tg], 0, 0, 0);
      acc[tg] = __builtin_amdgcn_mfma_f32_16x16x32_bf16(WF[tg][3], BF3, acc[tg], 0, 0, 0);
    }

    uint2* pf = pregS + (size_t)(gr*gstride + rec)*512 + (c + 16*kw);
    #pragma unroll
    for (int tg = 0; tg < 8; ++tg)
      pf[tg*64] = make_uint2(pkh(acc[tg][0]+bias[tg].x, acc[tg][1]+bias[tg].y),
                             pkh(acc[tg][2]+bias[tg].z, acc[tg][3]+bias[tg].w));

    // om bitmask: word per (row,step); bit i = mask_i
    unsigned int byteA =
        (ma0.x > .5f ? 1u : 0u) | (ma0.y > .5f ? 2u : 0u) |
        (ma0.z > .5f ? 4u : 0u) | (ma0.w > .5f ? 8u : 0u) |
        (ma1.x > .5f ? 16u : 0u) | (ma1.y > .5f ? 32u : 0u) |
        (ma1.z > .5f ? 64u : 0u) | (ma1.w > .5f ? 128u : 0u);
    unsigned int byteB =
        (mb0.x > .5f ? 1u : 0u) | (mb0.y > .5f ? 2u : 0u) |
        (mb0.z > .5f ? 4u : 0u) | (mb0.w > .5f ? 8u : 0u) |
        (mb1.x > .5f ? 16u : 0u) | (mb1.y > .5f ? 32u : 0u) |
        (mb1.z > .5f ? 64u : 0u) | (mb1.w > .5f ? 128u : 0u);
    unsigned char* omB = omS + ((size_t)(gr*gstride + rec)*16 + c)*8;
    omB[kw]     = (unsigned char)byteA;   // bits i = 8kw..8kw+7
    omB[4 + kw] = (unsigned char)byteB;   // bits i = 32+8kw..+7
  }
}

// ============ G2: gamma f16 (R13-proven, UNCHANGED) ============
__global__ __launch_bounds__(256) void g2_gam(
    const float* __restrict__ deltas, const float* __restrict__ W_decay,
    const float* __restrict__ b_decay, float* __restrict__ gamS, int gstride)
{
  const int tid = threadIdx.x, wv = tid >> 6, l = tid & 63;
  const int c = l & 15, kw = l >> 4;
  const int tch = blockIdx.x, gr = blockIdx.y;
  const int tbase = tch * 8;

  short8 AF[2][2];
  #pragma unroll
  for (int jt = 0; jt < 2; ++jt)
    #pragma unroll
    for (int kc = 0; kc < 2; ++kc)
      AF[jt][kc] = mkfrag(W_decay + (size_t)(16*jt + c)*64 + 32*kc + 8*kw);
  float4 bd0 = *(const float4*)(b_decay + 4*kw);
  float4 bd1 = *(const float4*)(b_decay + 16 + 4*kw);

  #pragma unroll 1
  for (int tt = 0; tt < 2; ++tt) {
    const int rec = tbase + wv*2 + tt;
    const float* dr = deltas + ((size_t)(gr*16 + c)*2048 + rec)*64;
    float4 da0 = *(const float4*)(dr + 8*kw),      da1 = *(const float4*)(dr + 8*kw + 4);
    float4 db0 = *(const float4*)(dr + 32 + 8*kw), db1 = *(const float4*)(dr + 32 + 8*kw + 4);
    short8 B0 = pk8(da0, da1), B1 = pk8(db0, db1);
    floatx4 zz = (floatx4){0.f, 0.f, 0.f, 0.f};
    floatx4 a0 = __builtin_amdgcn_mfma_f32_16x16x32_bf16(AF[0][0], B0, zz, 0, 0, 0);
    a0 = __builtin_amdgcn_mfma_f32_16x16x32_bf16(AF[0][1], B1, a0, 0, 0, 0);
    floatx4 a1 = __builtin_amdgcn_mfma_f32_16x16x32_bf16(AF[1][0], B0, zz, 0, 0, 0);
    a1 = __builtin_amdgcn_mfma_f32_16x16x32_bf16(AF[1][1], B1, a1, 0, 0, 0);
    float g0 = __builtin_amdgcn_exp2f(-fmaxf(a0[0]+bd0.x, 0.f) * L2E);
    float g1 = __builtin_amdgcn_exp2f(-fmaxf(a0[1]+bd0.y, 0.f) * L2E);
    float g2 = __builtin_amdgcn_exp2f(-fmaxf(a0[2]+bd0.z, 0.f) * L2E);
    float g3 = __builtin_amdgcn_exp2f(-fmaxf(a0[3]+bd0.w, 0.f) * L2E);
    float h0 = __builtin_amdgcn_exp2f(-fmaxf(a1[0]+bd1.x, 0.f) * L2E);
    float h1 = __builtin_amdgcn_exp2f(-fmaxf(a1[1]+bd1.y, 0.f) * L2E);
    float h2 = __builtin_amdgcn_exp2f(-fmaxf(a1[2]+bd1.z, 0.f) * L2E);
    float h3 = __builtin_amdgcn_exp2f(-fmaxf(a1[3]+bd1.w, 0.f) * L2E);
    uintx4 o = (uintx4){pkh(g0, g1), pkh(g2, g3), pkh(h0, h1), pkh(h2, h3)};
    ((uintx4*)gamS)[(size_t)(gr*gstride + rec)*64 + c + 16*kw] = o;
  }
}

// ============ P16: R13 recurrence, m1 stream -> om bitmask ============
#define PW(GI, GF, GG, GO, CC, HH) do { \
  float _si = __builtin_amdgcn_rcpf(1.f + __builtin_amdgcn_exp2f((GI) * -L2E)); \
  float _sf = __builtin_amdgcn_rcpf(1.f + __builtin_amdgcn_exp2f((GF) * -L2E)); \
  float _so = __builtin_amdgcn_rcpf(1.f + __builtin_amdgcn_exp2f((GO) * -L2E)); \
  float _tg = 1.f - 2.f*__builtin_amdgcn_rcpf(1.f + __builtin_amdgcn_exp2f((GG) * (2.f*L2E))); \
  float _cn = fmaf(_sf, (CC), _si*_tg); \
  float _tc = 1.f - 2.f*__builtin_amdgcn_rcpf(1.f + __builtin_amdgcn_exp2f(_cn * (2.f*L2E))); \
  (CC) = _cn; (HH) = _so * _tc; \
} while (0)

__global__ __launch_bounds__(128, 1) void p16_rnn(
    const float* __restrict__ W_hh, const float* __restrict__ W_reg,
    const float* __restrict__ W_ih, const float* __restrict__ b_reg,
    const float* __restrict__ W_out, const float* __restrict__ b_out,
    const uint2* __restrict__ pregS, const char* __restrict__ gamS,
    const unsigned char* __restrict__ omS, char* __restrict__ hdG,
    float* __restrict__ y, int gstride)
{
  const int tid = threadIdx.x, gr = blockIdx.x;
  const int wid = tid >> 6, l = tid & 63;
  const int b = l & 15, w = l >> 4;

  __shared__ __align__(16) char hdB[2 * 1536];
  __shared__ float yL[2][16][2];

  short8 WhhA[4], WxcA0[4], WxcA1[4], WregA[4];
  #pragma unroll
  for (int tt = 0; tt < 4; ++tt) {
    const int tg = 2*tt + wid;
    WhhA[tt]  = mkfrag(W_hh + (size_t)(16*tg + b)*32 + 8*w);
    WxcA0[tt] = mkfrag(W_ih + (size_t)(16*tg + b)*128 + 8*w);
    WxcA1[tt] = mkfrag(W_ih + (size_t)(16*tg + b)*128 + 32 + 8*w);
    WregA[tt] = mkfrag(W_reg + (size_t)(16*tt + b)*32 + 8*w);
  }
  floatx4 brC[4];
  #pragma unroll
  for (int t = 0; t < 4; ++t) {
    float4 v = *(const float4*)(b_reg + 16*t + 4*w);
    brC[t] = (floatx4){v.x, v.y, v.z, v.w};
  }

  float4 h = make_float4(0.f, 0.f, 0.f, 0.f);
  float4 cv = make_float4(0.f, 0.f, 0.f, 0.f);

  const uint2* pPreg = pregS + (size_t)gr*gstride*512 + l;
  const char*  gamB  = gamS + (size_t)gr*gstride*1024 + (size_t)(b + 16*w)*16 + wid*8;
  const unsigned char* omB = omS + (size_t)gr*gstride*128 + b*8;
  char* hdP = hdG + (size_t)gr*gstride*1024 + b*64 + wid*32 + w*8;

  uint2 PR[2][4], GM[2], OM[2];

  auto PREF = [&](int s, int j) {
    #pragma unroll
    for (int tt = 0; tt < 4; ++tt) PR[j][tt] = pPreg[(size_t)s*512 + (2*tt + wid)*64];
    GM[j] = *(const uint2*)(gamB + (size_t)s*1024);
    OM[j] = *(const uint2*)(omB + (size_t)s*128);
  };

  auto BODY = [&](int j, int par) {
    float2 g01 = uph(GM[j].x), g23 = uph(GM[j].y);
    float4 hd = make_float4(h.x*g01.x, h.y*g01.y, h.z*g23.x, h.w*g23.y);
    uint32_t K0 = pkbf(hd.x, hd.y), K1 = pkbf(hd.z, hd.w);
    *(uint2*)hdP = make_uint2(K0, K1);
    hdP += 1024;
    *(uint2*)(hdB + par*1536 + b*96 + wid*32 + w*8) = make_uint2(K0, K1);
    asm volatile("s_waitcnt lgkmcnt(0)" ::: "memory");
    __builtin_amdgcn_s_barrier();
    asm volatile("" ::: "memory");
    short8 Bhd = *(const short8*)(hdB + par*1536 + b*96 + w*16);

    floatx4 uu[4];
    #pragma unroll
    for (int t = 0; t < 4; ++t)
      uu[t] = __builtin_amdgcn_mfma_f32_16x16x32_bf16(WregA[t], Bhd, brC[t], 0, 0, 0);
    floatx4 ga[4];
    #pragma unroll
    for (int tt = 0; tt < 4; ++tt) {
      float2 p01 = uph(PR[j][tt].x), p23 = uph(PR[j][tt].y);
      floatx4 ci = {p01.x, p01.y, p23.x, p23.y};
      ga[tt] = __builtin_amdgcn_mfma_f32_16x16x32_bf16(WhhA[tt], Bhd, ci, 0, 0, 0);
    }

    uint32_t U[8];
    #pragma unroll
    for (int t = 0; t < 4; ++t) {
      uint32_t wsel = (t < 2) ? OM[j].x : OM[j].y;
      const int sh = 16*(t & 1) + 4*w;
      float v0 = ((wsel >> (sh + 0)) & 1u) ? 0.f : uu[t][0];
      float v1 = ((wsel >> (sh + 1)) & 1u) ? 0.f : uu[t][1];
      float v2 = ((wsel >> (sh + 2)) & 1u) ? 0.f : uu[t][2];
      float v3 = ((wsel >> (sh + 3)) & 1u) ? 0.f : uu[t][3];
      U[2*t]   = pkbf(v0, v1);
      U[2*t+1] = pkbf(v2, v3);
    }
    SWAP32(U[0], U[2]); SWAP32(U[1], U[3]);
    SWAP16(U[0], U[2]); SWAP16(U[1], U[3]);
    short8 Bv0 = u4s8(U[0], U[1], U[2], U[3]);
    SWAP32(U[4], U[6]); SWAP32(U[5], U[7]);
    SWAP16(U[4], U[6]); SWAP16(U[5], U[7]);
    short8 Bv1 = u4s8(U[4], U[5], U[6], U[7]);

    #pragma unroll
    for (int tt = 0; tt < 4; ++tt)
      ga[tt] = __builtin_amdgcn_mfma_f32_16x16x32_bf16(WxcA0[tt], Bv0, ga[tt], 0, 0, 0);
    #pragma unroll
    for (int tt = 0; tt < 4; ++tt)
      ga[tt] = __builtin_amdgcn_mfma_f32_16x16x32_bf16(WxcA1[tt], Bv1, ga[tt], 0, 0, 0);

    PW(ga[0][0], ga[1][0], ga[2][0], ga[3][0], cv.x, h.x);
    PW(ga[0][1], ga[1][1], ga[2][1], ga[3][1], cv.y, h.y);
    PW(ga[0][2], ga[1][2], ga[2][2], ga[3][2], cv.z, h.z);
    PW(ga[0][3], ga[1][3], ga[2][3], ga[3][3], cv.w, h.w);
  };

  PREF(0, 0); PREF(1, 1);
  #pragma unroll 1
  for (int s = 0; s < 2048; s += 2) {
    BODY(0, 0); PREF(s + 2, 0);
    BODY(1, 1); PREF(s + 3, 1);
  }

  // y head
  {
    auto d4 = [](float4 a, float4 bb) {
      return fmaf(a.x, bb.x, fmaf(a.y, bb.y, fmaf(a.z, bb.z, a.w*bb.w)));
    };
    float4 wo0 = *(const float4*)(W_out + wid*16 + 4*w);
    float4 wo1 = *(const float4*)(W_out + 32 + wid*16 + 4*w);
    float p0 = d4(h, wo0);
    float p1 = d4(h, wo1);
    p0 += __shfl_xor(p0, 16); p0 += __shfl_xor(p0, 32);
    p1 += __shfl_xor(p1, 16); p1 += __shfl_xor(p1, 32);
    if (l < 16) { yL[wid][l][0] = p0; yL[wid][l][1] = p1; }
    asm volatile("s_waitcnt lgkmcnt(0)" ::: "memory");
    __builtin_amdgcn_s_barrier();
    asm volatile("" ::: "memory");
    if (wid == 0 && l < 16) {
      y[(gr*16 + l)*2 + 0] = yL[0][l][0] + yL[1][l][0] + b_out[0];
      y[(gr*16 + l)*2 + 1] = yL[0][l][1] + yL[1][l][1] + b_out[1];
    }
  }
}

// ============ P16_POST: imp = bit ? x : (W_reg·hd + b_reg), fully parallel ============
__global__ __launch_bounds__(256) void p16_post(
    const float* __restrict__ W_reg, const float* __restrict__ b_reg,
    const char* __restrict__ hdG, const unsigned char* __restrict__ omS,
    const float* __restrict__ values, float* __restrict__ imp, int gstride)
{
  const int tid = threadIdx.x, wv = tid >> 6, l = tid & 63;
  const int c = l & 15, kw = l >> 4;
  const int tch = blockIdx.x, gr = blockIdx.y;
  const int tbase = tch * 8;

  short8 WA[4];
  #pragma unroll
  for (int t = 0; t < 4; ++t)
    WA[t] = mkfrag(W_reg + (size_t)(16*t + c)*32 + 8*kw);
  floatx4 brC[4];
  #pragma unroll
  for (int t = 0; t < 4; ++t) {
    float4 v = *(const float4*)(b_reg + 16*t + 4*kw);
    brC[t] = (floatx4){v.x, v.y, v.z, v.w};
  }

  #pragma unroll 1
  for (int tt = 0; tt < 2; ++tt) {
    const int rec = tbase + wv*2 + tt;
    short8 Bhd = *(const short8*)(hdG + (size_t)(gr*gstride + rec)*1024 + c*64 + kw*16);
    uint2 om = *(const uint2*)(omS + ((size_t)(gr*gstride + rec)*16 + c)*8);
    floatx4 uu[4];
    #pragma unroll
    for (int t = 0; t < 4; ++t)
      uu[t] = __builtin_amdgcn_mfma_f32_16x16x32_bf16(WA[t], Bhd, brC[t], 0, 0, 0);

    const size_t base = ((size_t)(gr*16 + c)*2048 + rec)*64 + 4*kw;
    const float* xsrc = values + base;
    float* dst = imp + base;
    #pragma unroll
    for (int t = 0; t < 4; ++t) {
      float4 xv = *(const float4*)(xsrc + 16*t);
      uint32_t wsel = (t < 2) ? om.x : om.y;
      const int sh = 16*(t & 1) + 4*kw;
      *(float4*)(dst + 16*t) = make_float4(
          ((wsel >> (sh + 0)) & 1u) ? xv.x : uu[t][0],
          ((wsel >> (sh + 1)) & 1u) ? xv.y : uu[t][1],
          ((wsel >> (sh + 2)) & 1u) ? xv.z : uu[t][2],
          ((wsel >> (sh + 3)) & 1u) ? xv.w : uu[t][3]);
    }
  }
}

extern "C" void kernel_launch(void* const* d_in, const int* in_sizes, int n_in,
                              void* d_out, int out_size, void* d_ws, size_t ws_size,
                              hipStream_t stream) {
  (void)in_sizes; (void)n_in; (void)out_size; (void)ws_size;
  const float* values  = (const float*)d_in[0];
  const float* masks   = (const float*)d_in[1];
  const float* deltas  = (const float*)d_in[2];
  const float* W_decay = (const float*)d_in[3];
  const float* b_decay = (const float*)d_in[4];
  const float* W_reg   = (const float*)d_in[5];
  const float* b_reg   = (const float*)d_in[6];
  const float* W_ih    = (const float*)d_in[7];
  const float* b_ih    = (const float*)d_in[8];
  const float* W_hh    = (const float*)d_in[9];
  const float* b_hh    = (const float*)d_in[10];
  const float* W_out   = (const float*)d_in[11];
  const float* b_out   = (const float*)d_in[12];
  float* y   = (float*)d_out;
  float* imp = (float*)d_out + 512;   // outputs: y [256,2] then imputations [256,2048,64]

  const int gstride = 2056;           // +8 pad for unconditional tail prefetch
  char* pregS = (char*)d_ws;                                   // 16*gstride*4096 B
  char* gamS  = pregS + (size_t)16*gstride*4096;               // 16*gstride*1024 B
  char* omS   = gamS  + (size_t)16*gstride*1024;               // 16*gstride*128 B
  char* hdG   = omS   + (size_t)16*gstride*128;                // 16*gstride*1024 B

  hipLaunchKernelGGL(g1_pre, dim3(256, 16), dim3(256), 0, stream,
                     values, masks, W_ih, b_ih, b_hh,
                     (uint2*)pregS, (unsigned char*)omS, gstride);
  hipLaunchKernelGGL(g2_gam, dim3(256, 16), dim3(256), 0, stream,
                     deltas, W_decay, b_decay, (float*)gamS, gstride);
  hipLaunchKernelGGL(p16_rnn, dim3(16), dim3(128), 0, stream,
                     W_hh, W_reg, W_ih, b_reg, W_out, b_out,
                     (const uint2*)pregS, gamS, (const unsigned char*)omS, hdG, y, gstride);
  hipLaunchKernelGGL(p16_post, dim3(256, 16), dim3(256), 0, stream,
                     W_reg, b_reg, hdG, (const unsigned char*)omS, values, imp, gstride);
}

// Round 17
// 1598.993 us; speedup vs baseline: 1.5540x; 1.1022x over previous
//
#include <hip/hip_runtime.h>
#include <stdint.h>

#define L2E 1.4426950408889634f

typedef __attribute__((ext_vector_type(8))) short short8;
typedef __attribute__((ext_vector_type(4))) float floatx4;
typedef __attribute__((ext_vector_type(4))) unsigned int uintx4;
typedef __attribute__((ext_vector_type(2))) _Float16 half2v;

__device__ __forceinline__ uint32_t pkbf(float lo, float hi) {
  uint32_t r;
  asm("v_cvt_pk_bf16_f32 %0, %1, %2" : "=v"(r) : "v"(lo), "v"(hi));
  return r;
}
__device__ __forceinline__ uint32_t pkh(float lo, float hi) {
  uint32_t r;
  asm("v_cvt_pkrtz_f16_f32 %0, %1, %2" : "=v"(r) : "v"(lo), "v"(hi));
  return r;
}
__device__ __forceinline__ float2 uph(uint32_t u) {
  union { uint32_t u; half2v h; } z; z.u = u;
  return make_float2((float)z.h.x, (float)z.h.y);
}
__device__ __forceinline__ short8 mkfrag(const float* p) {
  float4 a = *(const float4*)p;
  float4 b = *(const float4*)(p + 4);
  union { uint32_t u[4]; short8 s; } z;
  z.u[0] = pkbf(a.x, a.y); z.u[1] = pkbf(a.z, a.w);
  z.u[2] = pkbf(b.x, b.y); z.u[3] = pkbf(b.z, b.w);
  return z.s;
}
__device__ __forceinline__ short8 pk8(float4 a, float4 b) {
  union { uint32_t u[4]; short8 s; } z;
  z.u[0] = pkbf(a.x, a.y); z.u[1] = pkbf(a.z, a.w);
  z.u[2] = pkbf(b.x, b.y); z.u[3] = pkbf(b.z, b.w);
  return z.s;
}
__device__ __forceinline__ short8 u4s8(uint32_t a, uint32_t b, uint32_t c, uint32_t d) {
  union { uint32_t u[4]; short8 s; } z;
  z.u[0] = a; z.u[1] = b; z.u[2] = c; z.u[3] = d;
  return z.s;
}

#define SWAP32(a, b) asm("v_permlane32_swap_b32 %0, %1" : "+v"(a), "+v"(b))
#define SWAP16(a, b) asm("v_permlane16_swap_b32 %0, %1" : "+v"(a), "+v"(b))

// ============ G1: preg f16 (R13 layout) + m1 f16 (exact; R13 slot layout) + om bits ============
__global__ __launch_bounds__(256) void g1_pre(
    const float* __restrict__ values, const float* __restrict__ masks,
    const float* __restrict__ W_ih, const float* __restrict__ b_ih,
    const float* __restrict__ b_hh, uint2* __restrict__ pregS,
    uint2* __restrict__ m1hS, unsigned char* __restrict__ omS, int gstride)
{
  const int tid = threadIdx.x, wv = tid >> 6, l = tid & 63;
  const int c = l & 15, kw = l >> 4;
  const int tch = blockIdx.x, gr = blockIdx.y;
  const int tbase = tch * 8;

  short8 WF[8][4];
  #pragma unroll
  for (int tg = 0; tg < 8; ++tg)
    #pragma unroll
    for (int kc = 0; kc < 4; ++kc)
      WF[tg][kc] = mkfrag(W_ih + (size_t)(16*tg + c)*128 + 32*kc + 8*kw);

  float4 bias[8];
  #pragma unroll
  for (int tg = 0; tg < 8; ++tg) {
    float4 bi = *(const float4*)(b_ih + 16*tg + 4*kw);
    float4 bh = *(const float4*)(b_hh + 16*tg + 4*kw);
    bias[tg] = make_float4(bi.x+bh.x, bi.y+bh.y, bi.z+bh.z, bi.w+bh.w);
  }

  #pragma unroll 1
  for (int tt = 0; tt < 2; ++tt) {
    const int rec = tbase + wv*2 + tt;
    const size_t ibase = ((size_t)(gr*16 + c)*2048 + rec)*64;
    const float* xr = values + ibase;
    const float* mr = masks + ibase;
    float4 xa0 = *(const float4*)(xr + 8*kw),      xa1 = *(const float4*)(xr + 8*kw + 4);
    float4 xb0 = *(const float4*)(xr + 32 + 8*kw), xb1 = *(const float4*)(xr + 32 + 8*kw + 4);
    float4 ma0 = *(const float4*)(mr + 8*kw),      ma1 = *(const float4*)(mr + 8*kw + 4);
    float4 mb0 = *(const float4*)(mr + 32 + 8*kw), mb1 = *(const float4*)(mr + 32 + 8*kw + 4);
    float4 fa0 = make_float4(xa0.x*ma0.x, xa0.y*ma0.y, xa0.z*ma0.z, xa0.w*ma0.w);
    float4 fa1 = make_float4(xa1.x*ma1.x, xa1.y*ma1.y, xa1.z*ma1.z, xa1.w*ma1.w);
    float4 fb0 = make_float4(xb0.x*mb0.x, xb0.y*mb0.y, xb0.z*mb0.z, xb0.w*mb0.w);
    float4 fb1 = make_float4(xb1.x*mb1.x, xb1.y*mb1.y, xb1.z*mb1.z, xb1.w*mb1.w);

    short8 BF0 = pk8(fa0, fa1), BF1 = pk8(fb0, fb1);
    short8 BF2 = pk8(ma0, ma1), BF3 = pk8(mb0, mb1);

    floatx4 acc[8];
    #pragma unroll
    for (int tg = 0; tg < 8; ++tg) acc[tg] = (floatx4){0.f, 0.f, 0.f, 0.f};
    #pragma unroll
    for (int tg = 0; tg < 8; ++tg) {
      acc[tg] = __builtin_amdgcn_mfma_f32_16x16x32_bf16(WF[tg][0], BF0, acc[tg], 0, 0, 0);
      acc[tg] = __builtin_amdgcn_mfma_f32_16x16x32_bf16(WF[tg][1], BF1, acc[tg], 0, 0, 0);
      acc[tg] = __builtin_amdgcn_mfma_f32_16x16x32_bf16(WF[tg][2], BF2, acc[tg], 0, 0, 0);
      acc[tg] = __builtin_amdgcn_mfma_f32_16x16x32_bf16(WF[tg][3], BF3, acc[tg], 0, 0, 0);
    }

    uint2* pf = pregS + (size_t)(gr*gstride + rec)*512 + (c + 16*kw);
    #pragma unroll
    for (int tg = 0; tg < 8; ++tg)
      pf[tg*64] = make_uint2(pkh(acc[tg][0]+bias[tg].x, acc[tg][1]+bias[tg].y),
                             pkh(acc[tg][2]+bias[tg].z, acc[tg][3]+bias[tg].w));

    // m1 as f16 (values exactly 0.0/1.0 — bit-exact), R13 slot layout
    uint2* m1h = m1hS + (size_t)(gr*gstride + rec)*256;
    m1h[(2*kw+0)*16 + c] = make_uint2(pkh(1.f-ma0.x, 1.f-ma0.y), pkh(1.f-ma0.z, 1.f-ma0.w));
    m1h[(2*kw+1)*16 + c] = make_uint2(pkh(1.f-ma1.x, 1.f-ma1.y), pkh(1.f-ma1.z, 1.f-ma1.w));
    m1h[(8+2*kw)*16 + c] = make_uint2(pkh(1.f-mb0.x, 1.f-mb0.y), pkh(1.f-mb0.z, 1.f-mb0.w));
    m1h[(9+2*kw)*16 + c] = make_uint2(pkh(1.f-mb1.x, 1.f-mb1.y), pkh(1.f-mb1.z, 1.f-mb1.w));

    // om bitmask (R16-proven) for the post pass
    unsigned int byteA =
        (ma0.x > .5f ? 1u : 0u) | (ma0.y > .5f ? 2u : 0u) |
        (ma0.z > .5f ? 4u : 0u) | (ma0.w > .5f ? 8u : 0u) |
        (ma1.x > .5f ? 16u : 0u) | (ma1.y > .5f ? 32u : 0u) |
        (ma1.z > .5f ? 64u : 0u) | (ma1.w > .5f ? 128u : 0u);
    unsigned int byteB =
        (mb0.x > .5f ? 1u : 0u) | (mb0.y > .5f ? 2u : 0u) |
        (mb0.z > .5f ? 4u : 0u) | (mb0.w > .5f ? 8u : 0u) |
        (mb1.x > .5f ? 16u : 0u) | (mb1.y > .5f ? 32u : 0u) |
        (mb1.z > .5f ? 64u : 0u) | (mb1.w > .5f ? 128u : 0u);
    unsigned char* omB = omS + ((size_t)(gr*gstride + rec)*16 + c)*8;
    omB[kw]     = (unsigned char)byteA;
    omB[4 + kw] = (unsigned char)byteB;
  }
}

// ============ G2: gamma f16 (R13-proven, UNCHANGED) ============
__global__ __launch_bounds__(256) void g2_gam(
    const float* __restrict__ deltas, const float* __restrict__ W_decay,
    const float* __restrict__ b_decay, float* __restrict__ gamS, int gstride)
{
  const int tid = threadIdx.x, wv = tid >> 6, l = tid & 63;
  const int c = l & 15, kw = l >> 4;
  const int tch = blockIdx.x, gr = blockIdx.y;
  const int tbase = tch * 8;

  short8 AF[2][2];
  #pragma unroll
  for (int jt = 0; jt < 2; ++jt)
    #pragma unroll
    for (int kc = 0; kc < 2; ++kc)
      AF[jt][kc] = mkfrag(W_decay + (size_t)(16*jt + c)*64 + 32*kc + 8*kw);
  float4 bd0 = *(const float4*)(b_decay + 4*kw);
  float4 bd1 = *(const float4*)(b_decay + 16 + 4*kw);

  #pragma unroll 1
  for (int tt = 0; tt < 2; ++tt) {
    const int rec = tbase + wv*2 + tt;
    const float* dr = deltas + ((size_t)(gr*16 + c)*2048 + rec)*64;
    float4 da0 = *(const float4*)(dr + 8*kw),      da1 = *(const float4*)(dr + 8*kw + 4);
    float4 db0 = *(const float4*)(dr + 32 + 8*kw), db1 = *(const float4*)(dr + 32 + 8*kw + 4);
    short8 B0 = pk8(da0, da1), B1 = pk8(db0, db1);
    floatx4 zz = (floatx4){0.f, 0.f, 0.f, 0.f};
    floatx4 a0 = __builtin_amdgcn_mfma_f32_16x16x32_bf16(AF[0][0], B0, zz, 0, 0, 0);
    a0 = __builtin_amdgcn_mfma_f32_16x16x32_bf16(AF[0][1], B1, a0, 0, 0, 0);
    floatx4 a1 = __builtin_amdgcn_mfma_f32_16x16x32_bf16(AF[1][0], B0, zz, 0, 0, 0);
    a1 = __builtin_amdgcn_mfma_f32_16x16x32_bf16(AF[1][1], B1, a1, 0, 0, 0);
    float g0 = __builtin_amdgcn_exp2f(-fmaxf(a0[0]+bd0.x, 0.f) * L2E);
    float g1 = __builtin_amdgcn_exp2f(-fmaxf(a0[1]+bd0.y, 0.f) * L2E);
    float g2 = __builtin_amdgcn_exp2f(-fmaxf(a0[2]+bd0.z, 0.f) * L2E);
    float g3 = __builtin_amdgcn_exp2f(-fmaxf(a0[3]+bd0.w, 0.f) * L2E);
    float h0 = __builtin_amdgcn_exp2f(-fmaxf(a1[0]+bd1.x, 0.f) * L2E);
    float h1 = __builtin_amdgcn_exp2f(-fmaxf(a1[1]+bd1.y, 0.f) * L2E);
    float h2 = __builtin_amdgcn_exp2f(-fmaxf(a1[2]+bd1.z, 0.f) * L2E);
    float h3 = __builtin_amdgcn_exp2f(-fmaxf(a1[3]+bd1.w, 0.f) * L2E);
    uintx4 o = (uintx4){pkh(g0, g1), pkh(g2, g3), pkh(h0, h1), pkh(h2, h3)};
    ((uintx4*)gamS)[(size_t)(gr*gstride + rec)*64 + c + 16*kw] = o;
  }
}

// ============ P17: R13 recurrence, m1 stream f16 (bit-exact), stores hd only ============
#define PW(GI, GF, GG, GO, CC, HH) do { \
  float _si = __builtin_amdgcn_rcpf(1.f + __builtin_amdgcn_exp2f((GI) * -L2E)); \
  float _sf = __builtin_amdgcn_rcpf(1.f + __builtin_amdgcn_exp2f((GF) * -L2E)); \
  float _so = __builtin_amdgcn_rcpf(1.f + __builtin_amdgcn_exp2f((GO) * -L2E)); \
  float _tg = 1.f - 2.f*__builtin_amdgcn_rcpf(1.f + __builtin_amdgcn_exp2f((GG) * (2.f*L2E))); \
  float _cn = fmaf(_sf, (CC), _si*_tg); \
  float _tc = 1.f - 2.f*__builtin_amdgcn_rcpf(1.f + __builtin_amdgcn_exp2f(_cn * (2.f*L2E))); \
  (CC) = _cn; (HH) = _so * _tc; \
} while (0)

__global__ __launch_bounds__(128, 1) void p17_rnn(
    const float* __restrict__ W_hh, const float* __restrict__ W_reg,
    const float* __restrict__ W_ih, const float* __restrict__ b_reg,
    const float* __restrict__ W_out, const float* __restrict__ b_out,
    const uint2* __restrict__ pregS, const char* __restrict__ gamS,
    const uint2* __restrict__ m1hS, char* __restrict__ hdG,
    float* __restrict__ y, int gstride)
{
  const int tid = threadIdx.x, gr = blockIdx.x;
  const int wid = tid >> 6, l = tid & 63;
  const int b = l & 15, w = l >> 4;

  __shared__ __align__(16) char hdB[2 * 1536];
  __shared__ float yL[2][16][2];

  short8 WhhA[4], WxcA0[4], WxcA1[4], WregA[4];
  #pragma unroll
  for (int tt = 0; tt < 4; ++tt) {
    const int tg = 2*tt + wid;
    WhhA[tt]  = mkfrag(W_hh + (size_t)(16*tg + b)*32 + 8*w);
    WxcA0[tt] = mkfrag(W_ih + (size_t)(16*tg + b)*128 + 8*w);
    WxcA1[tt] = mkfrag(W_ih + (size_t)(16*tg + b)*128 + 32 + 8*w);
    WregA[tt] = mkfrag(W_reg + (size_t)(16*tt + b)*32 + 8*w);
  }
  floatx4 brC[4];
  #pragma unroll
  for (int t = 0; t < 4; ++t) {
    float4 v = *(const float4*)(b_reg + 16*t + 4*w);
    brC[t] = (floatx4){v.x, v.y, v.z, v.w};
  }

  float4 h = make_float4(0.f, 0.f, 0.f, 0.f);
  float4 cv = make_float4(0.f, 0.f, 0.f, 0.f);

  const uint2* pPreg = pregS + (size_t)gr*gstride*512 + l;
  const char*  gamB  = gamS + (size_t)gr*gstride*1024 + (size_t)(b + 16*w)*16 + wid*8;
  const uint2* pM1   = m1hS + (size_t)gr*gstride*256;
  char* hdP = hdG + (size_t)gr*gstride*1024 + b*64 + wid*32 + w*8;

  uint2 PR[2][4], GM[2], M1h[2][4];

  auto PREF = [&](int s, int j) {
    #pragma unroll
    for (int tt = 0; tt < 4; ++tt) PR[j][tt] = pPreg[(size_t)s*512 + (2*tt + wid)*64];
    GM[j] = *(const uint2*)(gamB + (size_t)s*1024);
    #pragma unroll
    for (int t = 0; t < 4; ++t) M1h[j][t] = pM1[(size_t)s*256 + (4*t + w)*16 + b];
  };

  auto BODY = [&](int j, int par) {
    float2 g01 = uph(GM[j].x), g23 = uph(GM[j].y);
    float4 hd = make_float4(h.x*g01.x, h.y*g01.y, h.z*g23.x, h.w*g23.y);
    uint32_t K0 = pkbf(hd.x, hd.y), K1 = pkbf(hd.z, hd.w);
    *(uint2*)hdP = make_uint2(K0, K1);
    hdP += 1024;
    *(uint2*)(hdB + par*1536 + b*96 + wid*32 + w*8) = make_uint2(K0, K1);
    asm volatile("s_waitcnt lgkmcnt(0)" ::: "memory");
    __builtin_amdgcn_s_barrier();
    asm volatile("" ::: "memory");
    short8 Bhd = *(const short8*)(hdB + par*1536 + b*96 + w*16);

    floatx4 uu[4];
    #pragma unroll
    for (int t = 0; t < 4; ++t)
      uu[t] = __builtin_amdgcn_mfma_f32_16x16x32_bf16(WregA[t], Bhd, brC[t], 0, 0, 0);
    floatx4 ga[4];
    #pragma unroll
    for (int tt = 0; tt < 4; ++tt) {
      float2 p01 = uph(PR[j][tt].x), p23 = uph(PR[j][tt].y);
      floatx4 ci = {p01.x, p01.y, p23.x, p23.y};
      ga[tt] = __builtin_amdgcn_mfma_f32_16x16x32_bf16(WhhA[tt], Bhd, ci, 0, 0, 0);
    }

    uint32_t U[8];
    #pragma unroll
    for (int t = 0; t < 4; ++t) {
      float2 m1a = uph(M1h[j][t].x), m1b = uph(M1h[j][t].y);
      float v0 = m1a.x*uu[t][0], v1 = m1a.y*uu[t][1];
      float v2 = m1b.x*uu[t][2], v3 = m1b.y*uu[t][3];
      U[2*t]   = pkbf(v0, v1);
      U[2*t+1] = pkbf(v2, v3);
    }
    SWAP32(U[0], U[2]); SWAP32(U[1], U[3]);
    SWAP16(U[0], U[2]); SWAP16(U[1], U[3]);
    short8 Bv0 = u4s8(U[0], U[1], U[2], U[3]);
    SWAP32(U[4], U[6]); SWAP32(U[5], U[7]);
    SWAP16(U[4], U[6]); SWAP16(U[5], U[7]);
    short8 Bv1 = u4s8(U[4], U[5], U[6], U[7]);

    #pragma unroll
    for (int tt = 0; tt < 4; ++tt)
      ga[tt] = __builtin_amdgcn_mfma_f32_16x16x32_bf16(WxcA0[tt], Bv0, ga[tt], 0, 0, 0);
    #pragma unroll
    for (int tt = 0; tt < 4; ++tt)
      ga[tt] = __builtin_amdgcn_mfma_f32_16x16x32_bf16(WxcA1[tt], Bv1, ga[tt], 0, 0, 0);

    PW(ga[0][0], ga[1][0], ga[2][0], ga[3][0], cv.x, h.x);
    PW(ga[0][1], ga[1][1], ga[2][1], ga[3][1], cv.y, h.y);
    PW(ga[0][2], ga[1][2], ga[2][2], ga[3][2], cv.z, h.z);
    PW(ga[0][3], ga[1][3], ga[2][3], ga[3][3], cv.w, h.w);
  };

  PREF(0, 0); PREF(1, 1);
  #pragma unroll 1
  for (int s = 0; s < 2048; s += 2) {
    BODY(0, 0); PREF(s + 2, 0);
    BODY(1, 1); PREF(s + 3, 1);
  }

  // y head
  {
    auto d4 = [](float4 a, float4 bb) {
      return fmaf(a.x, bb.x, fmaf(a.y, bb.y, fmaf(a.z, bb.z, a.w*bb.w)));
    };
    float4 wo0 = *(const float4*)(W_out + wid*16 + 4*w);
    float4 wo1 = *(const float4*)(W_out + 32 + wid*16 + 4*w);
    float p0 = d4(h, wo0);
    float p1 = d4(h, wo1);
    p0 += __shfl_xor(p0, 16); p0 += __shfl_xor(p0, 32);
    p1 += __shfl_xor(p1, 16); p1 += __shfl_xor(p1, 32);
    if (l < 16) { yL[wid][l][0] = p0; yL[wid][l][1] = p1; }
    asm volatile("s_waitcnt lgkmcnt(0)" ::: "memory");
    __builtin_amdgcn_s_barrier();
    asm volatile("" ::: "memory");
    if (wid == 0 && l < 16) {
      y[(gr*16 + l)*2 + 0] = yL[0][l][0] + yL[1][l][0] + b_out[0];
      y[(gr*16 + l)*2 + 1] = yL[0][l][1] + yL[1][l][1] + b_out[1];
    }
  }
}

// ============ P16_POST: imp = bit ? x : (W_reg·hd + b_reg) (R16-proven, UNCHANGED) ============
__global__ __launch_bounds__(256) void p16_post(
    const float* __restrict__ W_reg, const float* __restrict__ b_reg,
    const char* __restrict__ hdG, const unsigned char* __restrict__ omS,
    const float* __restrict__ values, float* __restrict__ imp, int gstride)
{
  const int tid = threadIdx.x, wv = tid >> 6, l = tid & 63;
  const int c = l & 15, kw = l >> 4;
  const int tch = blockIdx.x, gr = blockIdx.y;
  const int tbase = tch * 8;

  short8 WA[4];
  #pragma unroll
  for (int t = 0; t < 4; ++t)
    WA[t] = mkfrag(W_reg + (size_t)(16*t + c)*32 + 8*kw);
  floatx4 brC[4];
  #pragma unroll
  for (int t = 0; t < 4; ++t) {
    float4 v = *(const float4*)(b_reg + 16*t + 4*kw);
    brC[t] = (floatx4){v.x, v.y, v.z, v.w};
  }

  #pragma unroll 1
  for (int tt = 0; tt < 2; ++tt) {
    const int rec = tbase + wv*2 + tt;
    short8 Bhd = *(const short8*)(hdG + (size_t)(gr*gstride + rec)*1024 + c*64 + kw*16);
    uint2 om = *(const uint2*)(omS + ((size_t)(gr*gstride + rec)*16 + c)*8);
    floatx4 uu[4];
    #pragma unroll
    for (int t = 0; t < 4; ++t)
      uu[t] = __builtin_amdgcn_mfma_f32_16x16x32_bf16(WA[t], Bhd, brC[t], 0, 0, 0);

    const size_t base = ((size_t)(gr*16 + c)*2048 + rec)*64 + 4*kw;
    const float* xsrc = values + base;
    float* dst = imp + base;
    #pragma unroll
    for (int t = 0; t < 4; ++t) {
      float4 xv = *(const float4*)(xsrc + 16*t);
      uint32_t wsel = (t < 2) ? om.x : om.y;
      const int sh = 16*(t & 1) + 4*kw;
      *(float4*)(dst + 16*t) = make_float4(
          ((wsel >> (sh + 0)) & 1u) ? xv.x : uu[t][0],
          ((wsel >> (sh + 1)) & 1u) ? xv.y : uu[t][1],
          ((wsel >> (sh + 2)) & 1u) ? xv.z : uu[t][2],
          ((wsel >> (sh + 3)) & 1u) ? xv.w : uu[t][3]);
    }
  }
}

extern "C" void kernel_launch(void* const* d_in, const int* in_sizes, int n_in,
                              void* d_out, int out_size, void* d_ws, size_t ws_size,
                              hipStream_t stream) {
  (void)in_sizes; (void)n_in; (void)out_size; (void)ws_size;
  const float* values  = (const float*)d_in[0];
  const float* masks   = (const float*)d_in[1];
  const float* deltas  = (const float*)d_in[2];
  const float* W_decay = (const float*)d_in[3];
  const float* b_decay = (const float*)d_in[4];
  const float* W_reg   = (const float*)d_in[5];
  const float* b_reg   = (const float*)d_in[6];
  const float* W_ih    = (const float*)d_in[7];
  const float* b_ih    = (const float*)d_in[8];
  const float* W_hh    = (const float*)d_in[9];
  const float* b_hh    = (const float*)d_in[10];
  const float* W_out   = (const float*)d_in[11];
  const float* b_out   = (const float*)d_in[12];
  float* y   = (float*)d_out;
  float* imp = (float*)d_out + 512;   // outputs: y [256,2] then imputations [256,2048,64]

  const int gstride = 2056;           // +8 pad for unconditional tail prefetch
  char* pregS = (char*)d_ws;                                   // 16*gstride*4096 B
  char* gamS  = pregS + (size_t)16*gstride*4096;               // 16*gstride*1024 B
  char* m1hS  = gamS  + (size_t)16*gstride*1024;               // 16*gstride*2048 B
  char* omS   = m1hS  + (size_t)16*gstride*2048;               // 16*gstride*128 B
  char* hdG   = omS   + (size_t)16*gstride*128;                // 16*gstride*1024 B

  hipLaunchKernelGGL(g1_pre, dim3(256, 16), dim3(256), 0, stream,
                     values, masks, W_ih, b_ih, b_hh,
                     (uint2*)pregS, (uint2*)m1hS, (unsigned char*)omS, gstride);
  hipLaunchKernelGGL(g2_gam, dim3(256, 16), dim3(256), 0, stream,
                     deltas, W_decay, b_decay, (float*)gamS, gstride);
  hipLaunchKernelGGL(p17_rnn, dim3(16), dim3(128), 0, stream,
                     W_hh, W_reg, W_ih, b_reg, W_out, b_out,
                     (const uint2*)pregS, gamS, (const uint2*)m1hS, hdG, y, gstride);
  hipLaunchKernelGGL(p16_post, dim3(256, 16), dim3(256), 0, stream,
                     W_reg, b_reg, hdG, (const unsigned char*)omS, values, imp, gstride);
}